// Round 1
// baseline (298.602 us; speedup 1.0000x reference)
//
#include <hip/hip_runtime.h>
#include <hip/hip_bf16.h>

typedef __attribute__((ext_vector_type(8))) __bf16 bf16x8;
typedef __attribute__((ext_vector_type(2))) __bf16 bf16x2;
typedef __attribute__((ext_vector_type(4))) float floatx4;
typedef __attribute__((ext_vector_type(4))) unsigned short us4;
typedef __attribute__((ext_vector_type(8))) unsigned short us8;
typedef __attribute__((ext_vector_type(4))) short s16x4;
typedef __attribute__((ext_vector_type(2))) unsigned int uint2v;
typedef __attribute__((ext_vector_type(4))) unsigned int uint4v;

#define MFMA16(A, B, C) __builtin_amdgcn_mfma_f32_16x16x32_bf16((A), (B), (C), 0, 0, 0)
#define MFMA1K(A, B, C) __builtin_amdgcn_mfma_f32_16x16x16bf16_1k((A), (B), (C), 0, 0, 0)

#define LOG2E 1.44269504088896340736f

#if __has_builtin(__builtin_amdgcn_exp2f)
#define EXP2F(x) __builtin_amdgcn_exp2f(x)
#else
#define EXP2F(x) exp2f(x)
#endif

static __device__ __forceinline__ unsigned short f2bfbits(float f) {
    __hip_bfloat16 h = __float2bfloat16(f);
    union { __hip_bfloat16 h; unsigned short u; } cv;
    cv.h = h;
    return cv.u;
}
// fast bf16 RNE (finite moderate values only)
static __device__ __forceinline__ unsigned int rne32(float f) {
    unsigned int u = __builtin_bit_cast(unsigned int, f);
    return u + 0x7fffu + ((u >> 16) & 1u);
}
static __device__ __forceinline__ unsigned short rne16(float f) {
    return (unsigned short)(rne32(f) >> 16);
}

#if __has_builtin(__builtin_amdgcn_cvt_pk_bf16_f32)
static __device__ __forceinline__ s16x4 pack4(float e0, float e1, float e2, float e3) {
    bf16x2 lo = __builtin_amdgcn_cvt_pk_bf16_f32(e0, e1);
    bf16x2 hi = __builtin_amdgcn_cvt_pk_bf16_f32(e2, e3);
    uint2v u = {__builtin_bit_cast(unsigned int, lo), __builtin_bit_cast(unsigned int, hi)};
    return __builtin_bit_cast(s16x4, u);
}
static __device__ __forceinline__ bf16x8 cvt8(floatx4 a, floatx4 b) {
    bf16x2 p0 = __builtin_amdgcn_cvt_pk_bf16_f32(a[0], a[1]);
    bf16x2 p1 = __builtin_amdgcn_cvt_pk_bf16_f32(a[2], a[3]);
    bf16x2 p2 = __builtin_amdgcn_cvt_pk_bf16_f32(b[0], b[1]);
    bf16x2 p3 = __builtin_amdgcn_cvt_pk_bf16_f32(b[2], b[3]);
    uint4v u = {__builtin_bit_cast(unsigned int, p0), __builtin_bit_cast(unsigned int, p1),
                __builtin_bit_cast(unsigned int, p2), __builtin_bit_cast(unsigned int, p3)};
    return __builtin_bit_cast(bf16x8, u);
}
#else
static __device__ __forceinline__ s16x4 pack4(float e0, float e1, float e2, float e3) {
    unsigned int pa = __builtin_amdgcn_perm(rne32(e1), rne32(e0), 0x07060302u);
    unsigned int pb = __builtin_amdgcn_perm(rne32(e3), rne32(e2), 0x07060302u);
    uint2v u = {pa, pb};
    return __builtin_bit_cast(s16x4, u);
}
static __device__ __forceinline__ bf16x8 cvt8(floatx4 a, floatx4 b) {
    us8 u;
#pragma unroll
    for (int i = 0; i < 4; i++) { u[i] = rne16(a[i]); u[4 + i] = rne16(b[i]); }
    return __builtin_bit_cast(bf16x8, u);
}
#endif

static __device__ __forceinline__ bf16x8 load_bf8(const __hip_bfloat16* p) {
    return *reinterpret_cast<const bf16x8*>(p);
}
static __device__ __forceinline__ float bf2f(unsigned short u) {
    unsigned int w = ((unsigned int)u) << 16;
    return __builtin_bit_cast(float, w);
}

// Fragment layouts (16-row tile = 1024 bf16):
//   qf/kf[tile][h(2)][lane(64)][e(8)]: M[tile*16 + (lane&15)][h*32 + (lane>>4)*8 + e]
//   vfs[tile][lane(64)][t(4)][e(4)]: V[tile*16 + (lane>>4)*4 + e][t*16 + (lane&15)]
//     (paired so one dwordx4 load delivers two MFMA1K B-fragments)
// K is pre-scaled by log2(e) (weights+bias) so exp(s) == exp2(s').

// ---------------------------------------------------------------------------
// K0: wT[p][d][c] = dw_p[c] * pw_p[c][d]  (K scaled by log2e)
// ---------------------------------------------------------------------------
__global__ __launch_bounds__(256) void prep_w(
    const float* __restrict__ dwq, const float* __restrict__ pwq,
    const float* __restrict__ dwk, const float* __restrict__ pwk,
    const float* __restrict__ dwv, const float* __restrict__ pwv,
    __hip_bfloat16* __restrict__ wT)
{
    int idx = blockIdx.x * 256 + threadIdx.x;   // < 49152
    int p = idx >> 14;
    int r = idx & 16383;
    int d = r >> 8, c = r & 255;
    const float* dw = (p == 0) ? dwq : ((p == 1) ? dwk : dwv);
    const float* pw = (p == 0) ? pwq : ((p == 1) ? pwk : pwv);
    float scale = (p == 1) ? LOG2E : 1.0f;
    wT[idx] = __float2bfloat16(dw[c] * pw[c * 64 + d] * scale);
}

// ---------------------------------------------------------------------------
// K1: QKV projection, one wave per (tile, proj): 768 blocks.
// ---------------------------------------------------------------------------
__global__ __launch_bounds__(256) void proj_qkv(
    const float* __restrict__ x,
    const __hip_bfloat16* __restrict__ wT,
    const float* __restrict__ bqp, const float* __restrict__ bkp,
    const float* __restrict__ bvp,
    __hip_bfloat16* __restrict__ qf, __hip_bfloat16* __restrict__ kf,
    __hip_bfloat16* __restrict__ vf)
{
    int wg = blockIdx.x * 4 + (threadIdx.x >> 6);   // 0..3071
    int p = wg >> 10;                                // 0=q 1=k 2=v
    int wid = wg & 1023;                             // tile
    int lane = threadIdx.x & 63;
    int l15 = lane & 15, quad = lane >> 4;
    int strip = wid << 4;

    floatx4 acc[4];
#pragma unroll
    for (int t = 0; t < 4; t++) acc[t] = (floatx4){0.f, 0.f, 0.f, 0.f};

    const float* xrow = x + (strip + l15) * 256 + quad * 8;
    const __hip_bfloat16* wp = wT + p * 16384;
#pragma unroll
    for (int ks = 0; ks < 8; ks++) {
        floatx4 xa = *reinterpret_cast<const floatx4*>(xrow + ks * 32);
        floatx4 xb = *reinterpret_cast<const floatx4*>(xrow + ks * 32 + 4);
        bf16x8 a = cvt8(xa, xb);
#pragma unroll
        for (int t = 0; t < 4; t++) {
            bf16x8 b = load_bf8(wp + (t * 16 + l15) * 256 + ks * 32 + quad * 8);
            acc[t] = MFMA16(a, b, acc[t]);
        }
    }
    if (p < 2) {
        __hip_bfloat16* dst = (p == 0) ? qf : kf;
        const float* bias = (p == 0) ? bqp : bkp;
        float bscale = (p == 1) ? LOG2E : 1.0f;
#pragma unroll
        for (int t = 0; t < 4; t++) {
            float bsv = bias[t * 16 + l15] * bscale;
            int off0 = wid * 1024 + (t >> 1) * 512 +
                       (((((t & 1) << 1) | (l15 >> 3)) * 16 + quad * 4) * 8) + (l15 & 7);
#pragma unroll
            for (int r = 0; r < 4; r++)
                dst[off0 + r * 8] = __float2bfloat16(acc[t][r] + bsv);
        }
    } else {
#pragma unroll
        for (int t = 0; t < 4; t++) {
            float bsv = bvp[t * 16 + l15];
            us4 pk;
#pragma unroll
            for (int r = 0; r < 4; r++) pk[r] = f2bfbits(acc[t][r] + bsv);
            *reinterpret_cast<us4*>(vf + (wid * 4 + t) * 256 + lane * 4) = pk;
        }
    }
}

// ---------------------------------------------------------------------------
// K2: 1024 blocks x 512 thr; block = 1 i-tile, 8 waves split j.
// rl_i = 1/sum_j exp2(s'_ij); tail writes vfs (paired layout) = vf * rl.
// 4 blocks/CU -> 8 waves/SIMD resident.
// ---------------------------------------------------------------------------
__global__ __launch_bounds__(512, 8) void pass1_rl(
    const __hip_bfloat16* __restrict__ qf, const __hip_bfloat16* __restrict__ kf,
    const __hip_bfloat16* __restrict__ vf, __hip_bfloat16* __restrict__ vfs)
{
    int itg = blockIdx.x;                 // global i-tile 0..1023
    int n = itg >> 8;
    int jw = threadIdx.x >> 6;            // 0..7
    int lane = threadIdx.x & 63;
    int l15 = lane & 15, quad = lane >> 4;

    const __hip_bfloat16* kp = kf + itg * 1024 + lane * 8;
    bf16x8 a0 = load_bf8(kp);
    bf16x8 a1 = load_bf8(kp + 512);

    floatx4 ls = (floatx4){0.f, 0.f, 0.f, 0.f};
    const __hip_bfloat16* qp0 = qf + (n * 256 + jw * 32) * 1024 + lane * 8;
    for (int it = 0; it < 16; it++, qp0 += 2048) {
        bf16x8 b0 = load_bf8(qp0);
        bf16x8 b1 = load_bf8(qp0 + 512);
        bf16x8 b2 = load_bf8(qp0 + 1024);
        bf16x8 b3 = load_bf8(qp0 + 1536);
        floatx4 z = (floatx4){0.f, 0.f, 0.f, 0.f};
        floatx4 sA0 = MFMA16(a1, b1, MFMA16(a0, b0, z));
        floatx4 sA1 = MFMA16(a1, b3, MFMA16(a0, b2, z));
#pragma unroll
        for (int r = 0; r < 4; r++) ls[r] += EXP2F(sA0[r]) + EXP2F(sA1[r]);
    }
#pragma unroll
    for (int m = 1; m < 16; m <<= 1) {
#pragma unroll
        for (int r = 0; r < 4; r++) ls[r] += __shfl_xor(ls[r], m, 64);
    }
    __shared__ float red[8][16];
    __shared__ float rls[16];
    if (l15 == 0) {
#pragma unroll
        for (int r = 0; r < 4; r++) red[jw][quad * 4 + r] = ls[r];
    }
    __syncthreads();
    if (threadIdx.x < 16) {
        float tot = 0.f;
#pragma unroll
        for (int w = 0; w < 8; w++) tot += red[w][threadIdx.x];
        rls[threadIdx.x] = 1.0f / tot;
    }
    __syncthreads();
    // vfs(paired) = vf * rl(row); input elem m: t=m>>8, l=(m>>2)&63, e=m&3
    // row = (l>>4)*4 + e; out index = l*16 + t*4 + e
    int m0 = threadIdx.x * 2;             // 0..1022, e0 in {0,2}
    int t = m0 >> 8;
    int l = (m0 >> 2) & 63;
    int e0 = m0 & 3;
    int q2 = l >> 4;
    unsigned int vv = *reinterpret_cast<const unsigned int*>(
        reinterpret_cast<const unsigned short*>(vf) + itg * 1024 + m0);
    float f0 = bf2f((unsigned short)(vv & 0xffffu)) * rls[q2 * 4 + e0];
    float f1 = bf2f((unsigned short)(vv >> 16)) * rls[q2 * 4 + e0 + 1];
    unsigned int ov = (rne32(f0) >> 16) | (rne32(f1) & 0xffff0000u);
    *reinterpret_cast<unsigned int*>(
        reinterpret_cast<unsigned short*>(vfs) + itg * 1024 + l * 16 + t * 4 + e0) = ov;
}

// ---------------------------------------------------------------------------
// K3: attT partials. 128*NPART blocks x 256; wave = 2 j-tiles, ITERS i-iters.
// NPART=16 -> 2048 blocks = 8 blocks/CU = 8 waves/SIMD resident.
// P = exp2(s') packed in-register; V pre-scaled by rl, paired dwordx4 loads.
// ---------------------------------------------------------------------------
template<int ITERS, int IHB>
__global__ __launch_bounds__(256, 8) void pass2_att(
    const __hip_bfloat16* __restrict__ qf, const __hip_bfloat16* __restrict__ kf,
    const __hip_bfloat16* __restrict__ vfs,
    unsigned short* __restrict__ attp)
{
    int b = blockIdx.x;
    int ih = b & ((1 << IHB) - 1);
    int g = b >> IHB;            // 0..127
    int n = g >> 5;
    int jg = g & 31;
    int w = threadIdx.x >> 6;
    int jt0 = jg * 8 + w * 2;    // local j-tiles jt0, jt0+1
    int lane = threadIdx.x & 63;
    int l15 = lane & 15, quad = lane >> 4;

    const __hip_bfloat16* qp = qf + (n * 256 + jt0) * 1024 + lane * 8;
    bf16x8 bq00 = load_bf8(qp);
    bf16x8 bq01 = load_bf8(qp + 512);
    bf16x8 bq10 = load_bf8(qp + 1024);
    bf16x8 bq11 = load_bf8(qp + 1536);

    floatx4 acc0[4], acc1[4];
#pragma unroll
    for (int t = 0; t < 4; t++) {
        acc0[t] = (floatx4){0.f, 0.f, 0.f, 0.f};
        acc1[t] = (floatx4){0.f, 0.f, 0.f, 0.f};
    }

    int it0 = n * 256 + ih * ITERS;
    const __hip_bfloat16* kp = kf + it0 * 1024 + lane * 8;
    const __hip_bfloat16* vp = vfs + it0 * 1024 + lane * 16;
    for (int it = 0; it < ITERS; it++, kp += 1024, vp += 1024) {
        bf16x8 a0 = load_bf8(kp);
        bf16x8 a1 = load_bf8(kp + 512);
        floatx4 z = (floatx4){0.f, 0.f, 0.f, 0.f};
        floatx4 s0 = MFMA16(a1, bq01, MFMA16(a0, bq00, z));
        floatx4 s1 = MFMA16(a1, bq11, MFMA16(a0, bq10, z));
        s16x4 p0 = pack4(EXP2F(s0[0]), EXP2F(s0[1]), EXP2F(s0[2]), EXP2F(s0[3]));
        s16x4 p1 = pack4(EXP2F(s1[0]), EXP2F(s1[1]), EXP2F(s1[2]), EXP2F(s1[3]));
        us8 v01 = *reinterpret_cast<const us8*>(vp);
        us8 v23 = *reinterpret_cast<const us8*>(vp + 8);
        s16x4 bv0 = __builtin_bit_cast(s16x4, __builtin_shufflevector(v01, v01, 0, 1, 2, 3));
        s16x4 bv1 = __builtin_bit_cast(s16x4, __builtin_shufflevector(v01, v01, 4, 5, 6, 7));
        s16x4 bv2 = __builtin_bit_cast(s16x4, __builtin_shufflevector(v23, v23, 0, 1, 2, 3));
        s16x4 bv3 = __builtin_bit_cast(s16x4, __builtin_shufflevector(v23, v23, 4, 5, 6, 7));
        acc0[0] = MFMA1K(p0, bv0, acc0[0]);
        acc1[0] = MFMA1K(p1, bv0, acc1[0]);
        acc0[1] = MFMA1K(p0, bv1, acc0[1]);
        acc1[1] = MFMA1K(p1, bv1, acc1[1]);
        acc0[2] = MFMA1K(p0, bv2, acc0[2]);
        acc1[2] = MFMA1K(p1, bv2, acc1[2]);
        acc0[3] = MFMA1K(p0, bv3, acc0[3]);
        acc1[3] = MFMA1K(p1, bv3, acc1[3]);
    }
    unsigned short* op0 = attp + ih * 1048576;
#pragma unroll
    for (int t = 0; t < 4; t++) {
        s16x4 k0 = pack4(acc0[t][0], acc0[t][1], acc0[t][2], acc0[t][3]);
        s16x4 k1 = pack4(acc1[t][0], acc1[t][1], acc1[t][2], acc1[t][3]);
        unsigned short* op = op0 + (n * 64 + t * 16 + l15) * 4096 + jt0 * 16 + quad * 4;
        *reinterpret_cast<s16x4*>(op) = k0;
        *reinterpret_cast<s16x4*>(op + 16) = k1;
    }
}

// ---------------------------------------------------------------------------
// K4: final sepconv + residual, summing NPART bf16 i-partials.
// ---------------------------------------------------------------------------
template<int NPART>
__global__ __launch_bounds__(256) void final_out(
    const unsigned short* __restrict__ attp, const float* __restrict__ gco,
    const float* __restrict__ dwa, const float* __restrict__ pwa,
    const float* __restrict__ ba, float* __restrict__ out)
{
    int b = blockIdx.x;       // 2048 blocks
    int n = b >> 9;
    int hh = (b >> 3) & 63;
    int w0 = (b & 7) << 3;
    __shared__ float g[512];
    int tid = threadIdx.x;
    const unsigned short* ap = attp + (n * 64 + hh) * 4096 + w0 * 64;
    for (int jj = tid; jj < 512; jj += 256) {
        float v = 0.f;
#pragma unroll
        for (int ph = 0; ph < NPART; ph++) v += bf2f(ap[ph * 1048576 + jj]);
        g[jj] = v * dwa[jj & 63];
    }
    __syncthreads();
    float acc[8];
#pragma unroll
    for (int w = 0; w < 8; w++) acc[w] = 0.f;
    for (int cc = 0; cc < 64; cc++) {
        float p = pwa[cc * 256 + tid];
#pragma unroll
        for (int w = 0; w < 8; w++) acc[w] += g[w * 64 + cc] * p;
    }
    float bb = ba[tid];
#pragma unroll
    for (int w = 0; w < 8; w++) {
        int pos = (n * 64 + hh) * 64 + w0 + w;
        float gv = gco[pos * 256 + tid];
        out[pos * 256 + tid] = gv * (acc[w] + bb) + gv;
    }
}

// ---------------------------------------------------------------------------
extern "C" void kernel_launch(void* const* d_in, const int* in_sizes, int n_in,
                              void* d_out, int out_size, void* d_ws, size_t ws_size,
                              hipStream_t stream) {
    const float* x   = (const float*)d_in[0];
    const float* gco = (const float*)d_in[1];
    const float* dwq = (const float*)d_in[2];
    const float* pwq = (const float*)d_in[3];
    const float* bq  = (const float*)d_in[4];
    const float* dwk = (const float*)d_in[5];
    const float* pwk = (const float*)d_in[6];
    const float* bk  = (const float*)d_in[7];
    const float* dwv = (const float*)d_in[8];
    const float* pwv = (const float*)d_in[9];
    const float* bv  = (const float*)d_in[10];
    const float* dwa = (const float*)d_in[11];
    const float* pwa = (const float*)d_in[12];
    const float* ba  = (const float*)d_in[13];
    float* out = (float*)d_out;

    char* ws = (char*)d_ws;
    __hip_bfloat16* wT  = (__hip_bfloat16*)ws;                    // 98304 B
    __hip_bfloat16* qf  = (__hip_bfloat16*)(ws + 98304);          // 2 MB
    __hip_bfloat16* kf  = (__hip_bfloat16*)(ws + 2195456);        // 2 MB
    __hip_bfloat16* vf  = (__hip_bfloat16*)(ws + 4292608);        // 2 MB
    __hip_bfloat16* vfs = (__hip_bfloat16*)(ws + 6389760);        // 2 MB
    unsigned short* attp = (unsigned short*)(ws + 8486912);       // NPART x 2 MB bf16

    const size_t NEED16 = 8486912u + 16u * 2097152u;  // ~42 MB for 16 partials

    prep_w<<<192, 256, 0, stream>>>(dwq, pwq, dwk, pwk, dwv, pwv, wT);
    proj_qkv<<<768, 256, 0, stream>>>(x, wT, bq, bk, bv, qf, kf, vf);
    pass1_rl<<<1024, 512, 0, stream>>>(qf, kf, vf, vfs);
    if (ws_size >= NEED16) {
        pass2_att<16, 4><<<2048, 256, 0, stream>>>(qf, kf, vfs, attp);
        final_out<16><<<2048, 256, 0, stream>>>(attp, gco, dwa, pwa, ba, out);
    } else {
        pass2_att<32, 3><<<1024, 256, 0, stream>>>(qf, kf, vfs, attp);
        final_out<8><<<2048, 256, 0, stream>>>(attp, gco, dwa, pwa, ba, out);
    }
}

// Round 2
// 188.668 us; speedup vs baseline: 1.5827x; 1.5827x over previous
//
#include <hip/hip_runtime.h>
#include <hip/hip_bf16.h>

typedef __attribute__((ext_vector_type(8))) __bf16 bf16x8;
typedef __attribute__((ext_vector_type(2))) __bf16 bf16x2;
typedef __attribute__((ext_vector_type(4))) float floatx4;
typedef __attribute__((ext_vector_type(4))) unsigned short us4;
typedef __attribute__((ext_vector_type(8))) unsigned short us8;
typedef __attribute__((ext_vector_type(4))) short s16x4;
typedef __attribute__((ext_vector_type(2))) unsigned int uint2v;
typedef __attribute__((ext_vector_type(4))) unsigned int uint4v;

#define MFMA16(A, B, C) __builtin_amdgcn_mfma_f32_16x16x32_bf16((A), (B), (C), 0, 0, 0)
#define MFMA1K(A, B, C) __builtin_amdgcn_mfma_f32_16x16x16bf16_1k((A), (B), (C), 0, 0, 0)

#define LOG2E 1.44269504088896340736f

#if __has_builtin(__builtin_amdgcn_exp2f)
#define EXP2F(x) __builtin_amdgcn_exp2f(x)
#else
#define EXP2F(x) exp2f(x)
#endif

static __device__ __forceinline__ unsigned short f2bfbits(float f) {
    __hip_bfloat16 h = __float2bfloat16(f);
    union { __hip_bfloat16 h; unsigned short u; } cv;
    cv.h = h;
    return cv.u;
}
// fast bf16 RNE (finite moderate values only)
static __device__ __forceinline__ unsigned int rne32(float f) {
    unsigned int u = __builtin_bit_cast(unsigned int, f);
    return u + 0x7fffu + ((u >> 16) & 1u);
}
static __device__ __forceinline__ unsigned short rne16(float f) {
    return (unsigned short)(rne32(f) >> 16);
}

#if __has_builtin(__builtin_amdgcn_cvt_pk_bf16_f32)
static __device__ __forceinline__ s16x4 pack4(float e0, float e1, float e2, float e3) {
    bf16x2 lo = __builtin_amdgcn_cvt_pk_bf16_f32(e0, e1);
    bf16x2 hi = __builtin_amdgcn_cvt_pk_bf16_f32(e2, e3);
    uint2v u = {__builtin_bit_cast(unsigned int, lo), __builtin_bit_cast(unsigned int, hi)};
    return __builtin_bit_cast(s16x4, u);
}
static __device__ __forceinline__ bf16x8 cvt8(floatx4 a, floatx4 b) {
    bf16x2 p0 = __builtin_amdgcn_cvt_pk_bf16_f32(a[0], a[1]);
    bf16x2 p1 = __builtin_amdgcn_cvt_pk_bf16_f32(a[2], a[3]);
    bf16x2 p2 = __builtin_amdgcn_cvt_pk_bf16_f32(b[0], b[1]);
    bf16x2 p3 = __builtin_amdgcn_cvt_pk_bf16_f32(b[2], b[3]);
    uint4v u = {__builtin_bit_cast(unsigned int, p0), __builtin_bit_cast(unsigned int, p1),
                __builtin_bit_cast(unsigned int, p2), __builtin_bit_cast(unsigned int, p3)};
    return __builtin_bit_cast(bf16x8, u);
}
#else
static __device__ __forceinline__ s16x4 pack4(float e0, float e1, float e2, float e3) {
    unsigned int pa = __builtin_amdgcn_perm(rne32(e1), rne32(e0), 0x07060302u);
    unsigned int pb = __builtin_amdgcn_perm(rne32(e3), rne32(e2), 0x07060302u);
    uint2v u = {pa, pb};
    return __builtin_bit_cast(s16x4, u);
}
static __device__ __forceinline__ bf16x8 cvt8(floatx4 a, floatx4 b) {
    us8 u;
#pragma unroll
    for (int i = 0; i < 4; i++) { u[i] = rne16(a[i]); u[4 + i] = rne16(b[i]); }
    return __builtin_bit_cast(bf16x8, u);
}
#endif

static __device__ __forceinline__ bf16x8 load_bf8(const __hip_bfloat16* p) {
    return *reinterpret_cast<const bf16x8*>(p);
}
static __device__ __forceinline__ float bf2f(unsigned short u) {
    unsigned int w = ((unsigned int)u) << 16;
    return __builtin_bit_cast(float, w);
}

// Fragment layouts (16-row tile = 1024 bf16):
//   qf/kf[tile][h(2)][lane(64)][e(8)]: M[tile*16 + (lane&15)][h*32 + (lane>>4)*8 + e]
//   vfs[tile][lane(64)][t(4)][e(4)]: V[tile*16 + (lane>>4)*4 + e][t*16 + (lane&15)]
//     (paired so one dwordx4 load delivers two MFMA1K B-fragments)
// K is pre-scaled by log2(e) (weights+bias) so exp(s) == exp2(s').

// ---------------------------------------------------------------------------
// K0: wT[p][d][c] = dw_p[c] * pw_p[c][d]  (K scaled by log2e)
// ---------------------------------------------------------------------------
__global__ __launch_bounds__(256) void prep_w(
    const float* __restrict__ dwq, const float* __restrict__ pwq,
    const float* __restrict__ dwk, const float* __restrict__ pwk,
    const float* __restrict__ dwv, const float* __restrict__ pwv,
    __hip_bfloat16* __restrict__ wT)
{
    int idx = blockIdx.x * 256 + threadIdx.x;   // < 49152
    int p = idx >> 14;
    int r = idx & 16383;
    int d = r >> 8, c = r & 255;
    const float* dw = (p == 0) ? dwq : ((p == 1) ? dwk : dwv);
    const float* pw = (p == 0) ? pwq : ((p == 1) ? pwk : pwv);
    float scale = (p == 1) ? LOG2E : 1.0f;
    wT[idx] = __float2bfloat16(dw[c] * pw[c * 64 + d] * scale);
}

// ---------------------------------------------------------------------------
// K1: QKV projection, one wave per (tile, proj): 768 blocks.
// ---------------------------------------------------------------------------
__global__ __launch_bounds__(256) void proj_qkv(
    const float* __restrict__ x,
    const __hip_bfloat16* __restrict__ wT,
    const float* __restrict__ bqp, const float* __restrict__ bkp,
    const float* __restrict__ bvp,
    __hip_bfloat16* __restrict__ qf, __hip_bfloat16* __restrict__ kf,
    __hip_bfloat16* __restrict__ vf)
{
    int wg = blockIdx.x * 4 + (threadIdx.x >> 6);   // 0..3071
    int p = wg >> 10;                                // 0=q 1=k 2=v
    int wid = wg & 1023;                             // tile
    int lane = threadIdx.x & 63;
    int l15 = lane & 15, quad = lane >> 4;
    int strip = wid << 4;

    floatx4 acc[4];
#pragma unroll
    for (int t = 0; t < 4; t++) acc[t] = (floatx4){0.f, 0.f, 0.f, 0.f};

    const float* xrow = x + (strip + l15) * 256 + quad * 8;
    const __hip_bfloat16* wp = wT + p * 16384;
#pragma unroll
    for (int ks = 0; ks < 8; ks++) {
        floatx4 xa = *reinterpret_cast<const floatx4*>(xrow + ks * 32);
        floatx4 xb = *reinterpret_cast<const floatx4*>(xrow + ks * 32 + 4);
        bf16x8 a = cvt8(xa, xb);
#pragma unroll
        for (int t = 0; t < 4; t++) {
            bf16x8 b = load_bf8(wp + (t * 16 + l15) * 256 + ks * 32 + quad * 8);
            acc[t] = MFMA16(a, b, acc[t]);
        }
    }
    if (p < 2) {
        __hip_bfloat16* dst = (p == 0) ? qf : kf;
        const float* bias = (p == 0) ? bqp : bkp;
        float bscale = (p == 1) ? LOG2E : 1.0f;
#pragma unroll
        for (int t = 0; t < 4; t++) {
            float bsv = bias[t * 16 + l15] * bscale;
            int off0 = wid * 1024 + (t >> 1) * 512 +
                       (((((t & 1) << 1) | (l15 >> 3)) * 16 + quad * 4) * 8) + (l15 & 7);
#pragma unroll
            for (int r = 0; r < 4; r++)
                dst[off0 + r * 8] = __float2bfloat16(acc[t][r] + bsv);
        }
    } else {
#pragma unroll
        for (int t = 0; t < 4; t++) {
            float bsv = bvp[t * 16 + l15];
            us4 pk;
#pragma unroll
            for (int r = 0; r < 4; r++) pk[r] = f2bfbits(acc[t][r] + bsv);
            *reinterpret_cast<us4*>(vf + (wid * 4 + t) * 256 + lane * 4) = pk;
        }
    }
}

// ---------------------------------------------------------------------------
// K2: 1024 blocks x 512 thr; block = 1 i-tile, 8 waves split j.
// rl_i = 1/sum_j exp2(s'_ij); tail writes vfs (paired layout) = vf * rl.
// Plain launch bounds: do NOT cap registers (round-1 lesson: forcing 8
// waves/EU spilled the accumulators -> 400 MB/dispatch scratch traffic).
// ---------------------------------------------------------------------------
__global__ __launch_bounds__(512) void pass1_rl(
    const __hip_bfloat16* __restrict__ qf, const __hip_bfloat16* __restrict__ kf,
    const __hip_bfloat16* __restrict__ vf, __hip_bfloat16* __restrict__ vfs)
{
    int itg = blockIdx.x;                 // global i-tile 0..1023
    int n = itg >> 8;
    int jw = threadIdx.x >> 6;            // 0..7
    int lane = threadIdx.x & 63;
    int l15 = lane & 15, quad = lane >> 4;

    const __hip_bfloat16* kp = kf + itg * 1024 + lane * 8;
    bf16x8 a0 = load_bf8(kp);
    bf16x8 a1 = load_bf8(kp + 512);

    floatx4 ls = (floatx4){0.f, 0.f, 0.f, 0.f};
    const __hip_bfloat16* qp0 = qf + (n * 256 + jw * 32) * 1024 + lane * 8;
    for (int it = 0; it < 16; it++, qp0 += 2048) {
        bf16x8 b0 = load_bf8(qp0);
        bf16x8 b1 = load_bf8(qp0 + 512);
        bf16x8 b2 = load_bf8(qp0 + 1024);
        bf16x8 b3 = load_bf8(qp0 + 1536);
        floatx4 z = (floatx4){0.f, 0.f, 0.f, 0.f};
        floatx4 sA0 = MFMA16(a1, b1, MFMA16(a0, b0, z));
        floatx4 sA1 = MFMA16(a1, b3, MFMA16(a0, b2, z));
#pragma unroll
        for (int r = 0; r < 4; r++) ls[r] += EXP2F(sA0[r]) + EXP2F(sA1[r]);
    }
#pragma unroll
    for (int m = 1; m < 16; m <<= 1) {
#pragma unroll
        for (int r = 0; r < 4; r++) ls[r] += __shfl_xor(ls[r], m, 64);
    }
    __shared__ float red[8][16];
    __shared__ float rls[16];
    if (l15 == 0) {
#pragma unroll
        for (int r = 0; r < 4; r++) red[jw][quad * 4 + r] = ls[r];
    }
    __syncthreads();
    if (threadIdx.x < 16) {
        float tot = 0.f;
#pragma unroll
        for (int w = 0; w < 8; w++) tot += red[w][threadIdx.x];
        rls[threadIdx.x] = 1.0f / tot;
    }
    __syncthreads();
    // vfs(paired) = vf * rl(row); input elem m: t=m>>8, l=(m>>2)&63, e=m&3
    // row = (l>>4)*4 + e; out index = l*16 + t*4 + e
    int m0 = threadIdx.x * 2;             // 0..1022, e0 in {0,2}
    int t = m0 >> 8;
    int l = (m0 >> 2) & 63;
    int e0 = m0 & 3;
    int q2 = l >> 4;
    unsigned int vv = *reinterpret_cast<const unsigned int*>(
        reinterpret_cast<const unsigned short*>(vf) + itg * 1024 + m0);
    float f0 = bf2f((unsigned short)(vv & 0xffffu)) * rls[q2 * 4 + e0];
    float f1 = bf2f((unsigned short)(vv >> 16)) * rls[q2 * 4 + e0 + 1];
    unsigned int ov = (rne32(f0) >> 16) | (rne32(f1) & 0xffff0000u);
    *reinterpret_cast<unsigned int*>(
        reinterpret_cast<unsigned short*>(vfs) + itg * 1024 + l * 16 + t * 4 + e0) = ov;
}

// ---------------------------------------------------------------------------
// K3: attT partials. 128*NPART blocks x 256; wave = 2 j-tiles, ITERS i-iters.
// NPART=16 -> 2048 blocks = 8 blocks/CU available to the scheduler.
// Plain launch bounds (no register cap -- round-1 spill lesson).
// P = exp2(s') packed in-register; V pre-scaled by rl, paired dwordx4 loads.
// ---------------------------------------------------------------------------
template<int ITERS, int IHB>
__global__ __launch_bounds__(256) void pass2_att(
    const __hip_bfloat16* __restrict__ qf, const __hip_bfloat16* __restrict__ kf,
    const __hip_bfloat16* __restrict__ vfs,
    unsigned short* __restrict__ attp)
{
    int b = blockIdx.x;
    int ih = b & ((1 << IHB) - 1);
    int g = b >> IHB;            // 0..127
    int n = g >> 5;
    int jg = g & 31;
    int w = threadIdx.x >> 6;
    int jt0 = jg * 8 + w * 2;    // local j-tiles jt0, jt0+1
    int lane = threadIdx.x & 63;
    int l15 = lane & 15, quad = lane >> 4;

    const __hip_bfloat16* qp = qf + (n * 256 + jt0) * 1024 + lane * 8;
    bf16x8 bq00 = load_bf8(qp);
    bf16x8 bq01 = load_bf8(qp + 512);
    bf16x8 bq10 = load_bf8(qp + 1024);
    bf16x8 bq11 = load_bf8(qp + 1536);

    floatx4 acc0[4], acc1[4];
#pragma unroll
    for (int t = 0; t < 4; t++) {
        acc0[t] = (floatx4){0.f, 0.f, 0.f, 0.f};
        acc1[t] = (floatx4){0.f, 0.f, 0.f, 0.f};
    }

    int it0 = n * 256 + ih * ITERS;
    const __hip_bfloat16* kp = kf + it0 * 1024 + lane * 8;
    const __hip_bfloat16* vp = vfs + it0 * 1024 + lane * 16;
    for (int it = 0; it < ITERS; it++, kp += 1024, vp += 1024) {
        bf16x8 a0 = load_bf8(kp);
        bf16x8 a1 = load_bf8(kp + 512);
        floatx4 z = (floatx4){0.f, 0.f, 0.f, 0.f};
        floatx4 s0 = MFMA16(a1, bq01, MFMA16(a0, bq00, z));
        floatx4 s1 = MFMA16(a1, bq11, MFMA16(a0, bq10, z));
        s16x4 p0 = pack4(EXP2F(s0[0]), EXP2F(s0[1]), EXP2F(s0[2]), EXP2F(s0[3]));
        s16x4 p1 = pack4(EXP2F(s1[0]), EXP2F(s1[1]), EXP2F(s1[2]), EXP2F(s1[3]));
        us8 v01 = *reinterpret_cast<const us8*>(vp);
        us8 v23 = *reinterpret_cast<const us8*>(vp + 8);
        s16x4 bv0 = __builtin_bit_cast(s16x4, __builtin_shufflevector(v01, v01, 0, 1, 2, 3));
        s16x4 bv1 = __builtin_bit_cast(s16x4, __builtin_shufflevector(v01, v01, 4, 5, 6, 7));
        s16x4 bv2 = __builtin_bit_cast(s16x4, __builtin_shufflevector(v23, v23, 0, 1, 2, 3));
        s16x4 bv3 = __builtin_bit_cast(s16x4, __builtin_shufflevector(v23, v23, 4, 5, 6, 7));
        acc0[0] = MFMA1K(p0, bv0, acc0[0]);
        acc1[0] = MFMA1K(p1, bv0, acc1[0]);
        acc0[1] = MFMA1K(p0, bv1, acc0[1]);
        acc1[1] = MFMA1K(p1, bv1, acc1[1]);
        acc0[2] = MFMA1K(p0, bv2, acc0[2]);
        acc1[2] = MFMA1K(p1, bv2, acc1[2]);
        acc0[3] = MFMA1K(p0, bv3, acc0[3]);
        acc1[3] = MFMA1K(p1, bv3, acc1[3]);
    }
    unsigned short* op0 = attp + ih * 1048576;
#pragma unroll
    for (int t = 0; t < 4; t++) {
        s16x4 k0 = pack4(acc0[t][0], acc0[t][1], acc0[t][2], acc0[t][3]);
        s16x4 k1 = pack4(acc1[t][0], acc1[t][1], acc1[t][2], acc1[t][3]);
        unsigned short* op = op0 + (n * 64 + t * 16 + l15) * 4096 + jt0 * 16 + quad * 4;
        *reinterpret_cast<s16x4*>(op) = k0;
        *reinterpret_cast<s16x4*>(op + 16) = k1;
    }
}

// ---------------------------------------------------------------------------
// K4: final sepconv + residual, summing NPART bf16 i-partials.
// ---------------------------------------------------------------------------
template<int NPART>
__global__ __launch_bounds__(256) void final_out(
    const unsigned short* __restrict__ attp, const float* __restrict__ gco,
    const float* __restrict__ dwa, const float* __restrict__ pwa,
    const float* __restrict__ ba, float* __restrict__ out)
{
    int b = blockIdx.x;       // 2048 blocks
    int n = b >> 9;
    int hh = (b >> 3) & 63;
    int w0 = (b & 7) << 3;
    __shared__ float g[512];
    int tid = threadIdx.x;
    const unsigned short* ap = attp + (n * 64 + hh) * 4096 + w0 * 64;
    for (int jj = tid; jj < 512; jj += 256) {
        float v = 0.f;
#pragma unroll
        for (int ph = 0; ph < NPART; ph++) v += bf2f(ap[ph * 1048576 + jj]);
        g[jj] = v * dwa[jj & 63];
    }
    __syncthreads();
    float acc[8];
#pragma unroll
    for (int w = 0; w < 8; w++) acc[w] = 0.f;
    for (int cc = 0; cc < 64; cc++) {
        float p = pwa[cc * 256 + tid];
#pragma unroll
        for (int w = 0; w < 8; w++) acc[w] += g[w * 64 + cc] * p;
    }
    float bb = ba[tid];
#pragma unroll
    for (int w = 0; w < 8; w++) {
        int pos = (n * 64 + hh) * 64 + w0 + w;
        float gv = gco[pos * 256 + tid];
        out[pos * 256 + tid] = gv * (acc[w] + bb) + gv;
    }
}

// ---------------------------------------------------------------------------
extern "C" void kernel_launch(void* const* d_in, const int* in_sizes, int n_in,
                              void* d_out, int out_size, void* d_ws, size_t ws_size,
                              hipStream_t stream) {
    const float* x   = (const float*)d_in[0];
    const float* gco = (const float*)d_in[1];
    const float* dwq = (const float*)d_in[2];
    const float* pwq = (const float*)d_in[3];
    const float* bq  = (const float*)d_in[4];
    const float* dwk = (const float*)d_in[5];
    const float* pwk = (const float*)d_in[6];
    const float* bk  = (const float*)d_in[7];
    const float* dwv = (const float*)d_in[8];
    const float* pwv = (const float*)d_in[9];
    const float* bv  = (const float*)d_in[10];
    const float* dwa = (const float*)d_in[11];
    const float* pwa = (const float*)d_in[12];
    const float* ba  = (const float*)d_in[13];
    float* out = (float*)d_out;

    char* ws = (char*)d_ws;
    __hip_bfloat16* wT  = (__hip_bfloat16*)ws;                    // 98304 B
    __hip_bfloat16* qf  = (__hip_bfloat16*)(ws + 98304);          // 2 MB
    __hip_bfloat16* kf  = (__hip_bfloat16*)(ws + 2195456);        // 2 MB
    __hip_bfloat16* vf  = (__hip_bfloat16*)(ws + 4292608);        // 2 MB
    __hip_bfloat16* vfs = (__hip_bfloat16*)(ws + 6389760);        // 2 MB
    unsigned short* attp = (unsigned short*)(ws + 8486912);       // NPART x 2 MB bf16

    const size_t NEED16 = 8486912u + 16u * 2097152u;  // ~42 MB for 16 partials

    prep_w<<<192, 256, 0, stream>>>(dwq, pwq, dwk, pwk, dwv, pwv, wT);
    proj_qkv<<<768, 256, 0, stream>>>(x, wT, bq, bk, bv, qf, kf, vf);
    pass1_rl<<<1024, 512, 0, stream>>>(qf, kf, vf, vfs);
    if (ws_size >= NEED16) {
        pass2_att<16, 4><<<2048, 256, 0, stream>>>(qf, kf, vfs, attp);
        final_out<16><<<2048, 256, 0, stream>>>(attp, gco, dwa, pwa, ba, out);
    } else {
        pass2_att<32, 3><<<1024, 256, 0, stream>>>(qf, kf, vfs, attp);
        final_out<8><<<2048, 256, 0, stream>>>(attp, gco, dwa, pwa, ba, out);
    }
}

// Round 3
// 182.557 us; speedup vs baseline: 1.6357x; 1.0335x over previous
//
#include <hip/hip_runtime.h>
#include <hip/hip_bf16.h>

typedef __attribute__((ext_vector_type(8))) __bf16 bf16x8;
typedef __attribute__((ext_vector_type(2))) __bf16 bf16x2;
typedef __attribute__((ext_vector_type(4))) float floatx4;
typedef __attribute__((ext_vector_type(4))) unsigned short us4;
typedef __attribute__((ext_vector_type(8))) unsigned short us8;
typedef __attribute__((ext_vector_type(4))) short s16x4;
typedef __attribute__((ext_vector_type(2))) unsigned int uint2v;
typedef __attribute__((ext_vector_type(4))) unsigned int uint4v;

#define MFMA16(A, B, C) __builtin_amdgcn_mfma_f32_16x16x32_bf16((A), (B), (C), 0, 0, 0)
#define MFMA1K(A, B, C) __builtin_amdgcn_mfma_f32_16x16x16bf16_1k((A), (B), (C), 0, 0, 0)

#define LOG2E 1.44269504088896340736f

#if __has_builtin(__builtin_amdgcn_exp2f)
#define EXP2F(x) __builtin_amdgcn_exp2f(x)
#else
#define EXP2F(x) exp2f(x)
#endif

static __device__ __forceinline__ unsigned short f2bfbits(float f) {
    __hip_bfloat16 h = __float2bfloat16(f);
    union { __hip_bfloat16 h; unsigned short u; } cv;
    cv.h = h;
    return cv.u;
}
// fast bf16 RNE (finite moderate values only)
static __device__ __forceinline__ unsigned int rne32(float f) {
    unsigned int u = __builtin_bit_cast(unsigned int, f);
    return u + 0x7fffu + ((u >> 16) & 1u);
}
static __device__ __forceinline__ unsigned short rne16(float f) {
    return (unsigned short)(rne32(f) >> 16);
}

#if __has_builtin(__builtin_amdgcn_cvt_pk_bf16_f32)
static __device__ __forceinline__ s16x4 pack4(float e0, float e1, float e2, float e3) {
    bf16x2 lo = __builtin_amdgcn_cvt_pk_bf16_f32(e0, e1);
    bf16x2 hi = __builtin_amdgcn_cvt_pk_bf16_f32(e2, e3);
    uint2v u = {__builtin_bit_cast(unsigned int, lo), __builtin_bit_cast(unsigned int, hi)};
    return __builtin_bit_cast(s16x4, u);
}
static __device__ __forceinline__ bf16x8 cvt8(floatx4 a, floatx4 b) {
    bf16x2 p0 = __builtin_amdgcn_cvt_pk_bf16_f32(a[0], a[1]);
    bf16x2 p1 = __builtin_amdgcn_cvt_pk_bf16_f32(a[2], a[3]);
    bf16x2 p2 = __builtin_amdgcn_cvt_pk_bf16_f32(b[0], b[1]);
    bf16x2 p3 = __builtin_amdgcn_cvt_pk_bf16_f32(b[2], b[3]);
    uint4v u = {__builtin_bit_cast(unsigned int, p0), __builtin_bit_cast(unsigned int, p1),
                __builtin_bit_cast(unsigned int, p2), __builtin_bit_cast(unsigned int, p3)};
    return __builtin_bit_cast(bf16x8, u);
}
#else
static __device__ __forceinline__ s16x4 pack4(float e0, float e1, float e2, float e3) {
    unsigned int pa = __builtin_amdgcn_perm(rne32(e1), rne32(e0), 0x07060302u);
    unsigned int pb = __builtin_amdgcn_perm(rne32(e3), rne32(e2), 0x07060302u);
    uint2v u = {pa, pb};
    return __builtin_bit_cast(s16x4, u);
}
static __device__ __forceinline__ bf16x8 cvt8(floatx4 a, floatx4 b) {
    us8 u;
#pragma unroll
    for (int i = 0; i < 4; i++) { u[i] = rne16(a[i]); u[4 + i] = rne16(b[i]); }
    return __builtin_bit_cast(bf16x8, u);
}
#endif

static __device__ __forceinline__ bf16x8 load_bf8(const __hip_bfloat16* p) {
    return *reinterpret_cast<const bf16x8*>(p);
}
static __device__ __forceinline__ float bf2f(unsigned short u) {
    unsigned int w = ((unsigned int)u) << 16;
    return __builtin_bit_cast(float, w);
}

// Fragment layouts (16-row tile = 1024 bf16):
//   qf/kf[tile][h(2)][lane(64)][e(8)]: M[tile*16 + (lane&15)][h*32 + (lane>>4)*8 + e]
//   vf[tile][t(4)][lane(64)][e(4)]:  V[tile*16 + (lane>>4)*4 + e][t*16 + (lane&15)]
//   vfs[tile][lane(64)][t(4)][e(4)] (paired): one dwordx4 = two MFMA1K B-frags
// K is pre-scaled by log2(e) (weights+bias) so exp(s) == exp2(s').

// ---------------------------------------------------------------------------
// K0: wT[p][d][c] = dw_p[c] * pw_p[c][d]  (K scaled by log2e)
// ---------------------------------------------------------------------------
__global__ __launch_bounds__(256) void prep_w(
    const float* __restrict__ dwq, const float* __restrict__ pwq,
    const float* __restrict__ dwk, const float* __restrict__ pwk,
    const float* __restrict__ dwv, const float* __restrict__ pwv,
    __hip_bfloat16* __restrict__ wT)
{
    int idx = blockIdx.x * 256 + threadIdx.x;   // < 49152
    int p = idx >> 14;
    int r = idx & 16383;
    int d = r >> 8, c = r & 255;
    const float* dw = (p == 0) ? dwq : ((p == 1) ? dwk : dwv);
    const float* pw = (p == 0) ? pwq : ((p == 1) ? pwk : pwv);
    float scale = (p == 1) ? LOG2E : 1.0f;
    wT[idx] = __float2bfloat16(dw[c] * pw[c * 64 + d] * scale);
}

// ---------------------------------------------------------------------------
// K1: QKV projection, one wave per (tile, proj): 768 blocks.
// ---------------------------------------------------------------------------
__global__ __launch_bounds__(256) void proj_qkv(
    const float* __restrict__ x,
    const __hip_bfloat16* __restrict__ wT,
    const float* __restrict__ bqp, const float* __restrict__ bkp,
    const float* __restrict__ bvp,
    __hip_bfloat16* __restrict__ qf, __hip_bfloat16* __restrict__ kf,
    __hip_bfloat16* __restrict__ vf)
{
    int wg = blockIdx.x * 4 + (threadIdx.x >> 6);   // 0..3071
    int p = wg >> 10;                                // 0=q 1=k 2=v
    int wid = wg & 1023;                             // tile
    int lane = threadIdx.x & 63;
    int l15 = lane & 15, quad = lane >> 4;
    int strip = wid << 4;

    floatx4 acc[4];
#pragma unroll
    for (int t = 0; t < 4; t++) acc[t] = (floatx4){0.f, 0.f, 0.f, 0.f};

    const float* xrow = x + (strip + l15) * 256 + quad * 8;
    const __hip_bfloat16* wp = wT + p * 16384;
#pragma unroll
    for (int ks = 0; ks < 8; ks++) {
        floatx4 xa = *reinterpret_cast<const floatx4*>(xrow + ks * 32);
        floatx4 xb = *reinterpret_cast<const floatx4*>(xrow + ks * 32 + 4);
        bf16x8 a = cvt8(xa, xb);
#pragma unroll
        for (int t = 0; t < 4; t++) {
            bf16x8 b = load_bf8(wp + (t * 16 + l15) * 256 + ks * 32 + quad * 8);
            acc[t] = MFMA16(a, b, acc[t]);
        }
    }
    if (p < 2) {
        __hip_bfloat16* dst = (p == 0) ? qf : kf;
        const float* bias = (p == 0) ? bqp : bkp;
        float bscale = (p == 1) ? LOG2E : 1.0f;
#pragma unroll
        for (int t = 0; t < 4; t++) {
            float bsv = bias[t * 16 + l15] * bscale;
            int off0 = wid * 1024 + (t >> 1) * 512 +
                       (((((t & 1) << 1) | (l15 >> 3)) * 16 + quad * 4) * 8) + (l15 & 7);
#pragma unroll
            for (int r = 0; r < 4; r++)
                dst[off0 + r * 8] = __float2bfloat16(acc[t][r] + bsv);
        }
    } else {
#pragma unroll
        for (int t = 0; t < 4; t++) {
            float bsv = bvp[t * 16 + l15];
            us4 pk;
#pragma unroll
            for (int r = 0; r < 4; r++) pk[r] = f2bfbits(acc[t][r] + bsv);
            *reinterpret_cast<us4*>(vf + (wid * 4 + t) * 256 + lane * 4) = pk;
        }
    }
}

// ---------------------------------------------------------------------------
// K2: 512 blocks x 512 thr; block = 2 i-tiles (K-frag reuse: 8 MFMA / 4 Q
// loads), 8 waves split j. Round-2 lesson: 1 i-tile/block doubled Q L2
// traffic (256->512 MB) for no latency win. Tail writes vfs in the paired
// layout pass2 needs. Plain launch bounds (no register cap).
// ---------------------------------------------------------------------------
__global__ __launch_bounds__(512) void pass1_rl(
    const __hip_bfloat16* __restrict__ qf, const __hip_bfloat16* __restrict__ kf,
    const __hip_bfloat16* __restrict__ vf, __hip_bfloat16* __restrict__ vfs)
{
    int itg0 = blockIdx.x * 2;            // i-tiles itg0, itg0+1 (same n)
    int n = itg0 >> 8;
    int jw = threadIdx.x >> 6;            // 0..7
    int lane = threadIdx.x & 63;
    int l15 = lane & 15, quad = lane >> 4;

    const __hip_bfloat16* kp = kf + itg0 * 1024 + lane * 8;
    bf16x8 a0 = load_bf8(kp);
    bf16x8 a1 = load_bf8(kp + 512);
    bf16x8 a2 = load_bf8(kp + 1024);
    bf16x8 a3 = load_bf8(kp + 1536);

    floatx4 lsA = (floatx4){0.f, 0.f, 0.f, 0.f};
    floatx4 lsB = (floatx4){0.f, 0.f, 0.f, 0.f};
    const __hip_bfloat16* qp0 = qf + (n * 256 + jw * 32) * 1024 + lane * 8;
    for (int it = 0; it < 16; it++, qp0 += 2048) {
        bf16x8 b0 = load_bf8(qp0);
        bf16x8 b1 = load_bf8(qp0 + 512);
        bf16x8 b2 = load_bf8(qp0 + 1024);
        bf16x8 b3 = load_bf8(qp0 + 1536);
        floatx4 z = (floatx4){0.f, 0.f, 0.f, 0.f};
        floatx4 sA0 = MFMA16(a1, b1, MFMA16(a0, b0, z));
        floatx4 sA1 = MFMA16(a1, b3, MFMA16(a0, b2, z));
        floatx4 sB0 = MFMA16(a3, b1, MFMA16(a2, b0, z));
        floatx4 sB1 = MFMA16(a3, b3, MFMA16(a2, b2, z));
#pragma unroll
        for (int r = 0; r < 4; r++) {
            lsA[r] += EXP2F(sA0[r]) + EXP2F(sA1[r]);
            lsB[r] += EXP2F(sB0[r]) + EXP2F(sB1[r]);
        }
    }
#pragma unroll
    for (int m = 1; m < 16; m <<= 1) {
#pragma unroll
        for (int r = 0; r < 4; r++) {
            lsA[r] += __shfl_xor(lsA[r], m, 64);
            lsB[r] += __shfl_xor(lsB[r], m, 64);
        }
    }
    __shared__ float red[8][32];
    __shared__ float rls[32];
    if (l15 == 0) {
#pragma unroll
        for (int r = 0; r < 4; r++) {
            red[jw][quad * 4 + r] = lsA[r];
            red[jw][16 + quad * 4 + r] = lsB[r];
        }
    }
    __syncthreads();
    if (threadIdx.x < 32) {
        float tot = 0.f;
#pragma unroll
        for (int w = 0; w < 8; w++) tot += red[w][threadIdx.x];
        rls[threadIdx.x] = 1.0f / tot;
    }
    __syncthreads();
    // vfs(paired) = vf * rl(row); input elem m (within tile): t=m>>8,
    // l=(m>>2)&63, e=m&3; row=(l>>4)*4+e; out idx = l*16 + t*4 + e.
    int m0 = threadIdx.x * 4;             // 0..2044, covers 2 tiles
    int toff = m0 >> 10;                  // 0/1
    int mm = m0 & 1023;
    int t = mm >> 8;
    int l = (mm >> 2) & 63;
    int rb = toff * 16 + (l >> 4) * 4;
    us4 vv = *reinterpret_cast<const us4*>(
        reinterpret_cast<const unsigned short*>(vf) + itg0 * 1024 + m0);
    us4 ov;
#pragma unroll
    for (int r = 0; r < 4; r++) ov[r] = rne16(bf2f(vv[r]) * rls[rb + r]);
    *reinterpret_cast<us4*>(
        reinterpret_cast<unsigned short*>(vfs) + (itg0 + toff) * 1024 + l * 16 + t * 4) = ov;
}

// ---------------------------------------------------------------------------
// K3: attT partials. 128*NPART blocks x 256; wave = 2 j-tiles, ITERS i-iters.
// NPART=16 -> 2048 blocks = 8 blocks/CU available to the scheduler.
// Plain launch bounds (no register cap -- round-1 spill lesson).
// P = exp2(s') packed in-register; V pre-scaled by rl, paired dwordx4 loads.
// ---------------------------------------------------------------------------
template<int ITERS, int IHB>
__global__ __launch_bounds__(256) void pass2_att(
    const __hip_bfloat16* __restrict__ qf, const __hip_bfloat16* __restrict__ kf,
    const __hip_bfloat16* __restrict__ vfs,
    unsigned short* __restrict__ attp)
{
    int b = blockIdx.x;
    int ih = b & ((1 << IHB) - 1);
    int g = b >> IHB;            // 0..127
    int n = g >> 5;
    int jg = g & 31;
    int w = threadIdx.x >> 6;
    int jt0 = jg * 8 + w * 2;    // local j-tiles jt0, jt0+1
    int lane = threadIdx.x & 63;
    int l15 = lane & 15, quad = lane >> 4;

    const __hip_bfloat16* qp = qf + (n * 256 + jt0) * 1024 + lane * 8;
    bf16x8 bq00 = load_bf8(qp);
    bf16x8 bq01 = load_bf8(qp + 512);
    bf16x8 bq10 = load_bf8(qp + 1024);
    bf16x8 bq11 = load_bf8(qp + 1536);

    floatx4 acc0[4], acc1[4];
#pragma unroll
    for (int t = 0; t < 4; t++) {
        acc0[t] = (floatx4){0.f, 0.f, 0.f, 0.f};
        acc1[t] = (floatx4){0.f, 0.f, 0.f, 0.f};
    }

    int it0 = n * 256 + ih * ITERS;
    const __hip_bfloat16* kp = kf + it0 * 1024 + lane * 8;
    const __hip_bfloat16* vp = vfs + it0 * 1024 + lane * 16;
    for (int it = 0; it < ITERS; it++, kp += 1024, vp += 1024) {
        bf16x8 a0 = load_bf8(kp);
        bf16x8 a1 = load_bf8(kp + 512);
        floatx4 z = (floatx4){0.f, 0.f, 0.f, 0.f};
        floatx4 s0 = MFMA16(a1, bq01, MFMA16(a0, bq00, z));
        floatx4 s1 = MFMA16(a1, bq11, MFMA16(a0, bq10, z));
        s16x4 p0 = pack4(EXP2F(s0[0]), EXP2F(s0[1]), EXP2F(s0[2]), EXP2F(s0[3]));
        s16x4 p1 = pack4(EXP2F(s1[0]), EXP2F(s1[1]), EXP2F(s1[2]), EXP2F(s1[3]));
        us8 v01 = *reinterpret_cast<const us8*>(vp);
        us8 v23 = *reinterpret_cast<const us8*>(vp + 8);
        s16x4 bv0 = __builtin_bit_cast(s16x4, __builtin_shufflevector(v01, v01, 0, 1, 2, 3));
        s16x4 bv1 = __builtin_bit_cast(s16x4, __builtin_shufflevector(v01, v01, 4, 5, 6, 7));
        s16x4 bv2 = __builtin_bit_cast(s16x4, __builtin_shufflevector(v23, v23, 0, 1, 2, 3));
        s16x4 bv3 = __builtin_bit_cast(s16x4, __builtin_shufflevector(v23, v23, 4, 5, 6, 7));
        acc0[0] = MFMA1K(p0, bv0, acc0[0]);
        acc1[0] = MFMA1K(p1, bv0, acc1[0]);
        acc0[1] = MFMA1K(p0, bv1, acc0[1]);
        acc1[1] = MFMA1K(p1, bv1, acc1[1]);
        acc0[2] = MFMA1K(p0, bv2, acc0[2]);
        acc1[2] = MFMA1K(p1, bv2, acc1[2]);
        acc0[3] = MFMA1K(p0, bv3, acc0[3]);
        acc1[3] = MFMA1K(p1, bv3, acc1[3]);
    }
    unsigned short* op0 = attp + ih * 1048576;
#pragma unroll
    for (int t = 0; t < 4; t++) {
        s16x4 k0 = pack4(acc0[t][0], acc0[t][1], acc0[t][2], acc0[t][3]);
        s16x4 k1 = pack4(acc1[t][0], acc1[t][1], acc1[t][2], acc1[t][3]);
        unsigned short* op = op0 + (n * 64 + t * 16 + l15) * 4096 + jt0 * 16 + quad * 4;
        *reinterpret_cast<s16x4*>(op) = k0;
        *reinterpret_cast<s16x4*>(op + 16) = k1;
    }
}

// ---------------------------------------------------------------------------
// K4: final sepconv + residual, summing NPART bf16 i-partials.
// Partial reduction uses paired dword loads (2 jj per thread).
// ---------------------------------------------------------------------------
template<int NPART>
__global__ __launch_bounds__(256) void final_out(
    const unsigned short* __restrict__ attp, const float* __restrict__ gco,
    const float* __restrict__ dwa, const float* __restrict__ pwa,
    const float* __restrict__ ba, float* __restrict__ out)
{
    int b = blockIdx.x;       // 2048 blocks
    int n = b >> 9;
    int hh = (b >> 3) & 63;
    int w0 = (b & 7) << 3;
    __shared__ float g[512];
    int tid = threadIdx.x;
    const unsigned short* ap = attp + (n * 64 + hh) * 4096 + w0 * 64;
    {
        int jj0 = tid * 2;    // 256 threads x 2 = 512
        float v0 = 0.f, v1 = 0.f;
#pragma unroll
        for (int ph = 0; ph < NPART; ph++) {
            unsigned int u = *reinterpret_cast<const unsigned int*>(ap + ph * 1048576 + jj0);
            v0 += bf2f((unsigned short)(u & 0xffffu));
            v1 += bf2f((unsigned short)(u >> 16));
        }
        g[jj0] = v0 * dwa[jj0 & 63];
        g[jj0 + 1] = v1 * dwa[(jj0 + 1) & 63];
    }
    __syncthreads();
    float acc[8];
#pragma unroll
    for (int w = 0; w < 8; w++) acc[w] = 0.f;
    for (int cc = 0; cc < 64; cc++) {
        float p = pwa[cc * 256 + tid];
#pragma unroll
        for (int w = 0; w < 8; w++) acc[w] += g[w * 64 + cc] * p;
    }
    float bb = ba[tid];
#pragma unroll
    for (int w = 0; w < 8; w++) {
        int pos = (n * 64 + hh) * 64 + w0 + w;
        float gv = gco[pos * 256 + tid];
        out[pos * 256 + tid] = gv * (acc[w] + bb) + gv;
    }
}

// ---------------------------------------------------------------------------
extern "C" void kernel_launch(void* const* d_in, const int* in_sizes, int n_in,
                              void* d_out, int out_size, void* d_ws, size_t ws_size,
                              hipStream_t stream) {
    const float* x   = (const float*)d_in[0];
    const float* gco = (const float*)d_in[1];
    const float* dwq = (const float*)d_in[2];
    const float* pwq = (const float*)d_in[3];
    const float* bq  = (const float*)d_in[4];
    const float* dwk = (const float*)d_in[5];
    const float* pwk = (const float*)d_in[6];
    const float* bk  = (const float*)d_in[7];
    const float* dwv = (const float*)d_in[8];
    const float* pwv = (const float*)d_in[9];
    const float* bv  = (const float*)d_in[10];
    const float* dwa = (const float*)d_in[11];
    const float* pwa = (const float*)d_in[12];
    const float* ba  = (const float*)d_in[13];
    float* out = (float*)d_out;

    char* ws = (char*)d_ws;
    __hip_bfloat16* wT  = (__hip_bfloat16*)ws;                    // 98304 B
    __hip_bfloat16* qf  = (__hip_bfloat16*)(ws + 98304);          // 2 MB
    __hip_bfloat16* kf  = (__hip_bfloat16*)(ws + 2195456);        // 2 MB
    __hip_bfloat16* vf  = (__hip_bfloat16*)(ws + 4292608);        // 2 MB
    __hip_bfloat16* vfs = (__hip_bfloat16*)(ws + 6389760);        // 2 MB
    unsigned short* attp = (unsigned short*)(ws + 8486912);       // NPART x 2 MB bf16

    const size_t NEED16 = 8486912u + 16u * 2097152u;  // ~42 MB for 16 partials

    prep_w<<<192, 256, 0, stream>>>(dwq, pwq, dwk, pwk, dwv, pwv, wT);
    proj_qkv<<<768, 256, 0, stream>>>(x, wT, bq, bk, bv, qf, kf, vf);
    pass1_rl<<<512, 512, 0, stream>>>(qf, kf, vf, vfs);
    if (ws_size >= NEED16) {
        pass2_att<16, 4><<<2048, 256, 0, stream>>>(qf, kf, vfs, attp);
        final_out<16><<<2048, 256, 0, stream>>>(attp, gco, dwa, pwa, ba, out);
    } else {
        pass2_att<32, 3><<<1024, 256, 0, stream>>>(qf, kf, vfs, attp);
        final_out<8><<<2048, 256, 0, stream>>>(attp, gco, dwa, pwa, ba, out);
    }
}

// Round 4
// 177.380 us; speedup vs baseline: 1.6834x; 1.0292x over previous
//
#include <hip/hip_runtime.h>
#include <hip/hip_bf16.h>

typedef __attribute__((ext_vector_type(8))) __bf16 bf16x8;
typedef __attribute__((ext_vector_type(2))) __bf16 bf16x2;
typedef __attribute__((ext_vector_type(4))) float floatx4;
typedef __attribute__((ext_vector_type(4))) unsigned short us4;
typedef __attribute__((ext_vector_type(8))) unsigned short us8;
typedef __attribute__((ext_vector_type(4))) short s16x4;
typedef __attribute__((ext_vector_type(2))) unsigned int uint2v;
typedef __attribute__((ext_vector_type(4))) unsigned int uint4v;

#define MFMA16(A, B, C) __builtin_amdgcn_mfma_f32_16x16x32_bf16((A), (B), (C), 0, 0, 0)
#define MFMA1K(A, B, C) __builtin_amdgcn_mfma_f32_16x16x16bf16_1k((A), (B), (C), 0, 0, 0)

#define LOG2E 1.44269504088896340736f

#if __has_builtin(__builtin_amdgcn_exp2f)
#define EXP2F(x) __builtin_amdgcn_exp2f(x)
#else
#define EXP2F(x) exp2f(x)
#endif

static __device__ __forceinline__ unsigned short f2bfbits(float f) {
    __hip_bfloat16 h = __float2bfloat16(f);
    union { __hip_bfloat16 h; unsigned short u; } cv;
    cv.h = h;
    return cv.u;
}
// fast bf16 RNE (finite moderate values only)
static __device__ __forceinline__ unsigned int rne32(float f) {
    unsigned int u = __builtin_bit_cast(unsigned int, f);
    return u + 0x7fffu + ((u >> 16) & 1u);
}
static __device__ __forceinline__ unsigned short rne16(float f) {
    return (unsigned short)(rne32(f) >> 16);
}

#if __has_builtin(__builtin_amdgcn_cvt_pk_bf16_f32)
static __device__ __forceinline__ s16x4 pack4(float e0, float e1, float e2, float e3) {
    bf16x2 lo = __builtin_amdgcn_cvt_pk_bf16_f32(e0, e1);
    bf16x2 hi = __builtin_amdgcn_cvt_pk_bf16_f32(e2, e3);
    uint2v u = {__builtin_bit_cast(unsigned int, lo), __builtin_bit_cast(unsigned int, hi)};
    return __builtin_bit_cast(s16x4, u);
}
static __device__ __forceinline__ bf16x8 cvt8(floatx4 a, floatx4 b) {
    bf16x2 p0 = __builtin_amdgcn_cvt_pk_bf16_f32(a[0], a[1]);
    bf16x2 p1 = __builtin_amdgcn_cvt_pk_bf16_f32(a[2], a[3]);
    bf16x2 p2 = __builtin_amdgcn_cvt_pk_bf16_f32(b[0], b[1]);
    bf16x2 p3 = __builtin_amdgcn_cvt_pk_bf16_f32(b[2], b[3]);
    uint4v u = {__builtin_bit_cast(unsigned int, p0), __builtin_bit_cast(unsigned int, p1),
                __builtin_bit_cast(unsigned int, p2), __builtin_bit_cast(unsigned int, p3)};
    return __builtin_bit_cast(bf16x8, u);
}
#else
static __device__ __forceinline__ s16x4 pack4(float e0, float e1, float e2, float e3) {
    unsigned int pa = __builtin_amdgcn_perm(rne32(e1), rne32(e0), 0x07060302u);
    unsigned int pb = __builtin_amdgcn_perm(rne32(e3), rne32(e2), 0x07060302u);
    uint2v u = {pa, pb};
    return __builtin_bit_cast(s16x4, u);
}
static __device__ __forceinline__ bf16x8 cvt8(floatx4 a, floatx4 b) {
    us8 u;
#pragma unroll
    for (int i = 0; i < 4; i++) { u[i] = rne16(a[i]); u[4 + i] = rne16(b[i]); }
    return __builtin_bit_cast(bf16x8, u);
}
#endif

static __device__ __forceinline__ bf16x8 load_bf8(const __hip_bfloat16* p) {
    return *reinterpret_cast<const bf16x8*>(p);
}
static __device__ __forceinline__ float bf2f(unsigned short u) {
    unsigned int w = ((unsigned int)u) << 16;
    return __builtin_bit_cast(float, w);
}

// Fragment layouts (16-row tile = 1024 bf16):
//   qf/kf[tile][h(2)][lane(64)][e(8)]: M[tile*16 + (lane&15)][h*32 + (lane>>4)*8 + e]
//   vf[tile][t(4)][lane(64)][e(4)]:  V[tile*16 + (lane>>4)*4 + e][t*16 + (lane&15)]
//   vfs[tile][lane(64)][t(4)][e(4)] (paired): one dwordx4 = two MFMA1K B-frags
// K is pre-scaled by log2(e) (weights+bias) so exp(s) == exp2(s').

// ---------------------------------------------------------------------------
// K0: wT[p][d][c] = dw_p[c] * pw_p[c][d]  (K scaled by log2e)
// ---------------------------------------------------------------------------
__global__ __launch_bounds__(256) void prep_w(
    const float* __restrict__ dwq, const float* __restrict__ pwq,
    const float* __restrict__ dwk, const float* __restrict__ pwk,
    const float* __restrict__ dwv, const float* __restrict__ pwv,
    __hip_bfloat16* __restrict__ wT)
{
    int idx = blockIdx.x * 256 + threadIdx.x;   // < 49152
    int p = idx >> 14;
    int r = idx & 16383;
    int d = r >> 8, c = r & 255;
    const float* dw = (p == 0) ? dwq : ((p == 1) ? dwk : dwv);
    const float* pw = (p == 0) ? pwq : ((p == 1) ? pwk : pwv);
    float scale = (p == 1) ? LOG2E : 1.0f;
    wT[idx] = __float2bfloat16(dw[c] * pw[c * 64 + d] * scale);
}

// ---------------------------------------------------------------------------
// K1: QKV projection, one wave per (tile, proj): 768 blocks.
// ---------------------------------------------------------------------------
__global__ __launch_bounds__(256) void proj_qkv(
    const float* __restrict__ x,
    const __hip_bfloat16* __restrict__ wT,
    const float* __restrict__ bqp, const float* __restrict__ bkp,
    const float* __restrict__ bvp,
    __hip_bfloat16* __restrict__ qf, __hip_bfloat16* __restrict__ kf,
    __hip_bfloat16* __restrict__ vf)
{
    int wg = blockIdx.x * 4 + (threadIdx.x >> 6);   // 0..3071
    int p = wg >> 10;                                // 0=q 1=k 2=v
    int wid = wg & 1023;                             // tile
    int lane = threadIdx.x & 63;
    int l15 = lane & 15, quad = lane >> 4;
    int strip = wid << 4;

    floatx4 acc[4];
#pragma unroll
    for (int t = 0; t < 4; t++) acc[t] = (floatx4){0.f, 0.f, 0.f, 0.f};

    const float* xrow = x + (strip + l15) * 256 + quad * 8;
    const __hip_bfloat16* wp = wT + p * 16384;
#pragma unroll
    for (int ks = 0; ks < 8; ks++) {
        floatx4 xa = *reinterpret_cast<const floatx4*>(xrow + ks * 32);
        floatx4 xb = *reinterpret_cast<const floatx4*>(xrow + ks * 32 + 4);
        bf16x8 a = cvt8(xa, xb);
#pragma unroll
        for (int t = 0; t < 4; t++) {
            bf16x8 b = load_bf8(wp + (t * 16 + l15) * 256 + ks * 32 + quad * 8);
            acc[t] = MFMA16(a, b, acc[t]);
        }
    }
    if (p < 2) {
        __hip_bfloat16* dst = (p == 0) ? qf : kf;
        const float* bias = (p == 0) ? bqp : bkp;
        float bscale = (p == 1) ? LOG2E : 1.0f;
#pragma unroll
        for (int t = 0; t < 4; t++) {
            float bsv = bias[t * 16 + l15] * bscale;
            int off0 = wid * 1024 + (t >> 1) * 512 +
                       (((((t & 1) << 1) | (l15 >> 3)) * 16 + quad * 4) * 8) + (l15 & 7);
#pragma unroll
            for (int r = 0; r < 4; r++)
                dst[off0 + r * 8] = __float2bfloat16(acc[t][r] + bsv);
        }
    } else {
#pragma unroll
        for (int t = 0; t < 4; t++) {
            float bsv = bvp[t * 16 + l15];
            us4 pk;
#pragma unroll
            for (int r = 0; r < 4; r++) pk[r] = f2bfbits(acc[t][r] + bsv);
            *reinterpret_cast<us4*>(vf + (wid * 4 + t) * 256 + lane * 4) = pk;
        }
    }
}

// ---------------------------------------------------------------------------
// K2: 512 blocks x 512 thr; block = 2 i-tiles (K-frag reuse: 8 MFMA / 4 Q
// loads), 8 waves split j. Tail writes vfs in the paired layout pass2 needs.
// Plain launch bounds (no register cap).
// ---------------------------------------------------------------------------
__global__ __launch_bounds__(512) void pass1_rl(
    const __hip_bfloat16* __restrict__ qf, const __hip_bfloat16* __restrict__ kf,
    const __hip_bfloat16* __restrict__ vf, __hip_bfloat16* __restrict__ vfs)
{
    int itg0 = blockIdx.x * 2;            // i-tiles itg0, itg0+1 (same n)
    int n = itg0 >> 8;
    int jw = threadIdx.x >> 6;            // 0..7
    int lane = threadIdx.x & 63;
    int l15 = lane & 15, quad = lane >> 4;

    const __hip_bfloat16* kp = kf + itg0 * 1024 + lane * 8;
    bf16x8 a0 = load_bf8(kp);
    bf16x8 a1 = load_bf8(kp + 512);
    bf16x8 a2 = load_bf8(kp + 1024);
    bf16x8 a3 = load_bf8(kp + 1536);

    floatx4 lsA = (floatx4){0.f, 0.f, 0.f, 0.f};
    floatx4 lsB = (floatx4){0.f, 0.f, 0.f, 0.f};
    const __hip_bfloat16* qp0 = qf + (n * 256 + jw * 32) * 1024 + lane * 8;
    for (int it = 0; it < 16; it++, qp0 += 2048) {
        bf16x8 b0 = load_bf8(qp0);
        bf16x8 b1 = load_bf8(qp0 + 512);
        bf16x8 b2 = load_bf8(qp0 + 1024);
        bf16x8 b3 = load_bf8(qp0 + 1536);
        floatx4 z = (floatx4){0.f, 0.f, 0.f, 0.f};
        floatx4 sA0 = MFMA16(a1, b1, MFMA16(a0, b0, z));
        floatx4 sA1 = MFMA16(a1, b3, MFMA16(a0, b2, z));
        floatx4 sB0 = MFMA16(a3, b1, MFMA16(a2, b0, z));
        floatx4 sB1 = MFMA16(a3, b3, MFMA16(a2, b2, z));
#pragma unroll
        for (int r = 0; r < 4; r++) {
            lsA[r] += EXP2F(sA0[r]) + EXP2F(sA1[r]);
            lsB[r] += EXP2F(sB0[r]) + EXP2F(sB1[r]);
        }
    }
#pragma unroll
    for (int m = 1; m < 16; m <<= 1) {
#pragma unroll
        for (int r = 0; r < 4; r++) {
            lsA[r] += __shfl_xor(lsA[r], m, 64);
            lsB[r] += __shfl_xor(lsB[r], m, 64);
        }
    }
    __shared__ float red[8][32];
    __shared__ float rls[32];
    if (l15 == 0) {
#pragma unroll
        for (int r = 0; r < 4; r++) {
            red[jw][quad * 4 + r] = lsA[r];
            red[jw][16 + quad * 4 + r] = lsB[r];
        }
    }
    __syncthreads();
    if (threadIdx.x < 32) {
        float tot = 0.f;
#pragma unroll
        for (int w = 0; w < 8; w++) tot += red[w][threadIdx.x];
        rls[threadIdx.x] = 1.0f / tot;
    }
    __syncthreads();
    // vfs(paired) = vf * rl(row); input elem m (within tile): t=m>>8,
    // l=(m>>2)&63, e=m&3; row=(l>>4)*4+e; out idx = l*16 + t*4 + e.
    int m0 = threadIdx.x * 4;             // 0..2044, covers 2 tiles
    int toff = m0 >> 10;                  // 0/1
    int mm = m0 & 1023;
    int t = mm >> 8;
    int l = (mm >> 2) & 63;
    int rb = toff * 16 + (l >> 4) * 4;
    us4 vv = *reinterpret_cast<const us4*>(
        reinterpret_cast<const unsigned short*>(vf) + itg0 * 1024 + m0);
    us4 ov;
#pragma unroll
    for (int r = 0; r < 4; r++) ov[r] = rne16(bf2f(vv[r]) * rls[rb + r]);
    *reinterpret_cast<us4*>(
        reinterpret_cast<unsigned short*>(vfs) + (itg0 + toff) * 1024 + l * 16 + t * 4) = ov;
}

// ---------------------------------------------------------------------------
// K3: attT partials. Latency-bound diagnosis (true MFMA~5%, VALU~14% after
// un-inflating the gfx94x-fallback counters): attack with per-wave ILP, not
// occupancy. Wave = 4 j-tiles (4 independent QK->exp->PV chains), block =
// 16 j-tiles, grid = 4n x 16jg x 8ih = 512 blocks, ITERS=32 i-tiles.
// Explicit 2-stage load pipeline keeps next iter's K/V in flight under
// current compute. NPART=8 partials (16-split bought nothing, cost final).
// ---------------------------------------------------------------------------
template<int ITERS, int IHB>
__global__ __launch_bounds__(256) void pass2_att(
    const __hip_bfloat16* __restrict__ qf, const __hip_bfloat16* __restrict__ kf,
    const __hip_bfloat16* __restrict__ vfs,
    unsigned short* __restrict__ attp)
{
    int b = blockIdx.x;
    int ih = b & ((1 << IHB) - 1);
    int g = b >> IHB;            // 0..63
    int n = g >> 4;
    int jg = g & 15;
    int w = threadIdx.x >> 6;
    int jt0 = jg * 16 + w * 4;   // local j-tiles jt0..jt0+3
    int lane = threadIdx.x & 63;
    int l15 = lane & 15, quad = lane >> 4;

    const __hip_bfloat16* qp = qf + (n * 256 + jt0) * 1024 + lane * 8;
    bf16x8 bq0a = load_bf8(qp);
    bf16x8 bq0b = load_bf8(qp + 512);
    bf16x8 bq1a = load_bf8(qp + 1024);
    bf16x8 bq1b = load_bf8(qp + 1536);
    bf16x8 bq2a = load_bf8(qp + 2048);
    bf16x8 bq2b = load_bf8(qp + 2560);
    bf16x8 bq3a = load_bf8(qp + 3072);
    bf16x8 bq3b = load_bf8(qp + 3584);

    floatx4 acc0[4], acc1[4], acc2[4], acc3[4];
#pragma unroll
    for (int t = 0; t < 4; t++) {
        acc0[t] = (floatx4){0.f, 0.f, 0.f, 0.f};
        acc1[t] = (floatx4){0.f, 0.f, 0.f, 0.f};
        acc2[t] = (floatx4){0.f, 0.f, 0.f, 0.f};
        acc3[t] = (floatx4){0.f, 0.f, 0.f, 0.f};
    }

    int it0 = n * 256 + ih * ITERS;
    const __hip_bfloat16* kp = kf + it0 * 1024 + lane * 8;
    const __hip_bfloat16* vp = vfs + it0 * 1024 + lane * 16;

    // stage 0 loads
    bf16x8 a0 = load_bf8(kp);
    bf16x8 a1 = load_bf8(kp + 512);
    us8 v01 = *reinterpret_cast<const us8*>(vp);
    us8 v23 = *reinterpret_cast<const us8*>(vp + 8);

    for (int it = 0; it < ITERS; it++) {
        // issue next iter's loads first (stay in flight under compute)
        bf16x8 na0, na1; us8 nv01, nv23;
        if (it + 1 < ITERS) {
            const __hip_bfloat16* kpn = kp + 1024;
            const __hip_bfloat16* vpn = vp + 1024;
            na0 = load_bf8(kpn);
            na1 = load_bf8(kpn + 512);
            nv01 = *reinterpret_cast<const us8*>(vpn);
            nv23 = *reinterpret_cast<const us8*>(vpn + 8);
        }
        floatx4 z = (floatx4){0.f, 0.f, 0.f, 0.f};
        floatx4 s0 = MFMA16(a1, bq0b, MFMA16(a0, bq0a, z));
        floatx4 s1 = MFMA16(a1, bq1b, MFMA16(a0, bq1a, z));
        floatx4 s2 = MFMA16(a1, bq2b, MFMA16(a0, bq2a, z));
        floatx4 s3 = MFMA16(a1, bq3b, MFMA16(a0, bq3a, z));
        s16x4 p0 = pack4(EXP2F(s0[0]), EXP2F(s0[1]), EXP2F(s0[2]), EXP2F(s0[3]));
        s16x4 p1 = pack4(EXP2F(s1[0]), EXP2F(s1[1]), EXP2F(s1[2]), EXP2F(s1[3]));
        s16x4 p2 = pack4(EXP2F(s2[0]), EXP2F(s2[1]), EXP2F(s2[2]), EXP2F(s2[3]));
        s16x4 p3 = pack4(EXP2F(s3[0]), EXP2F(s3[1]), EXP2F(s3[2]), EXP2F(s3[3]));
        s16x4 bv0 = __builtin_bit_cast(s16x4, __builtin_shufflevector(v01, v01, 0, 1, 2, 3));
        s16x4 bv1 = __builtin_bit_cast(s16x4, __builtin_shufflevector(v01, v01, 4, 5, 6, 7));
        s16x4 bv2 = __builtin_bit_cast(s16x4, __builtin_shufflevector(v23, v23, 0, 1, 2, 3));
        s16x4 bv3 = __builtin_bit_cast(s16x4, __builtin_shufflevector(v23, v23, 4, 5, 6, 7));
        acc0[0] = MFMA1K(p0, bv0, acc0[0]);
        acc1[0] = MFMA1K(p1, bv0, acc1[0]);
        acc2[0] = MFMA1K(p2, bv0, acc2[0]);
        acc3[0] = MFMA1K(p3, bv0, acc3[0]);
        acc0[1] = MFMA1K(p0, bv1, acc0[1]);
        acc1[1] = MFMA1K(p1, bv1, acc1[1]);
        acc2[1] = MFMA1K(p2, bv1, acc2[1]);
        acc3[1] = MFMA1K(p3, bv1, acc3[1]);
        acc0[2] = MFMA1K(p0, bv2, acc0[2]);
        acc1[2] = MFMA1K(p1, bv2, acc1[2]);
        acc2[2] = MFMA1K(p2, bv2, acc2[2]);
        acc3[2] = MFMA1K(p3, bv2, acc3[2]);
        acc0[3] = MFMA1K(p0, bv3, acc0[3]);
        acc1[3] = MFMA1K(p1, bv3, acc1[3]);
        acc2[3] = MFMA1K(p2, bv3, acc2[3]);
        acc3[3] = MFMA1K(p3, bv3, acc3[3]);
        a0 = na0; a1 = na1; v01 = nv01; v23 = nv23;
        kp += 1024; vp += 1024;
    }
    unsigned short* op0 = attp + ih * 1048576;
#pragma unroll
    for (int t = 0; t < 4; t++) {
        s16x4 k0 = pack4(acc0[t][0], acc0[t][1], acc0[t][2], acc0[t][3]);
        s16x4 k1 = pack4(acc1[t][0], acc1[t][1], acc1[t][2], acc1[t][3]);
        s16x4 k2 = pack4(acc2[t][0], acc2[t][1], acc2[t][2], acc2[t][3]);
        s16x4 k3 = pack4(acc3[t][0], acc3[t][1], acc3[t][2], acc3[t][3]);
        unsigned short* op = op0 + (n * 64 + t * 16 + l15) * 4096 + jt0 * 16 + quad * 4;
        *reinterpret_cast<s16x4*>(op) = k0;
        *reinterpret_cast<s16x4*>(op + 16) = k1;
        *reinterpret_cast<s16x4*>(op + 32) = k2;
        *reinterpret_cast<s16x4*>(op + 48) = k3;
    }
}

// ---------------------------------------------------------------------------
// K4: final sepconv + residual, summing NPART bf16 i-partials.
// Partial reduction uses paired dword loads (2 jj per thread).
// ---------------------------------------------------------------------------
template<int NPART>
__global__ __launch_bounds__(256) void final_out(
    const unsigned short* __restrict__ attp, const float* __restrict__ gco,
    const float* __restrict__ dwa, const float* __restrict__ pwa,
    const float* __restrict__ ba, float* __restrict__ out)
{
    int b = blockIdx.x;       // 2048 blocks
    int n = b >> 9;
    int hh = (b >> 3) & 63;
    int w0 = (b & 7) << 3;
    __shared__ float g[512];
    int tid = threadIdx.x;
    const unsigned short* ap = attp + (n * 64 + hh) * 4096 + w0 * 64;
    {
        int jj0 = tid * 2;    // 256 threads x 2 = 512
        float v0 = 0.f, v1 = 0.f;
#pragma unroll
        for (int ph = 0; ph < NPART; ph++) {
            unsigned int u = *reinterpret_cast<const unsigned int*>(ap + ph * 1048576 + jj0);
            v0 += bf2f((unsigned short)(u & 0xffffu));
            v1 += bf2f((unsigned short)(u >> 16));
        }
        g[jj0] = v0 * dwa[jj0 & 63];
        g[jj0 + 1] = v1 * dwa[(jj0 + 1) & 63];
    }
    __syncthreads();
    float acc[8];
#pragma unroll
    for (int w = 0; w < 8; w++) acc[w] = 0.f;
    for (int cc = 0; cc < 64; cc++) {
        float p = pwa[cc * 256 + tid];
#pragma unroll
        for (int w = 0; w < 8; w++) acc[w] += g[w * 64 + cc] * p;
    }
    float bb = ba[tid];
#pragma unroll
    for (int w = 0; w < 8; w++) {
        int pos = (n * 64 + hh) * 64 + w0 + w;
        float gv = gco[pos * 256 + tid];
        out[pos * 256 + tid] = gv * (acc[w] + bb) + gv;
    }
}

// ---------------------------------------------------------------------------
extern "C" void kernel_launch(void* const* d_in, const int* in_sizes, int n_in,
                              void* d_out, int out_size, void* d_ws, size_t ws_size,
                              hipStream_t stream) {
    const float* x   = (const float*)d_in[0];
    const float* gco = (const float*)d_in[1];
    const float* dwq = (const float*)d_in[2];
    const float* pwq = (const float*)d_in[3];
    const float* bq  = (const float*)d_in[4];
    const float* dwk = (const float*)d_in[5];
    const float* pwk = (const float*)d_in[6];
    const float* bk  = (const float*)d_in[7];
    const float* dwv = (const float*)d_in[8];
    const float* pwv = (const float*)d_in[9];
    const float* bv  = (const float*)d_in[10];
    const float* dwa = (const float*)d_in[11];
    const float* pwa = (const float*)d_in[12];
    const float* ba  = (const float*)d_in[13];
    float* out = (float*)d_out;

    char* ws = (char*)d_ws;
    __hip_bfloat16* wT  = (__hip_bfloat16*)ws;                    // 98304 B
    __hip_bfloat16* qf  = (__hip_bfloat16*)(ws + 98304);          // 2 MB
    __hip_bfloat16* kf  = (__hip_bfloat16*)(ws + 2195456);        // 2 MB
    __hip_bfloat16* vf  = (__hip_bfloat16*)(ws + 4292608);        // 2 MB
    __hip_bfloat16* vfs = (__hip_bfloat16*)(ws + 6389760);        // 2 MB
    unsigned short* attp = (unsigned short*)(ws + 8486912);       // 8 x 2 MB bf16

    prep_w<<<192, 256, 0, stream>>>(dwq, pwq, dwk, pwk, dwv, pwv, wT);
    proj_qkv<<<768, 256, 0, stream>>>(x, wT, bq, bk, bv, qf, kf, vf);
    pass1_rl<<<512, 512, 0, stream>>>(qf, kf, vf, vfs);
    pass2_att<32, 3><<<512, 256, 0, stream>>>(qf, kf, vfs, attp);
    final_out<8><<<2048, 256, 0, stream>>>(attp, gco, dwa, pwa, ba, out);
}

// Round 5
// 169.687 us; speedup vs baseline: 1.7597x; 1.0453x over previous
//
#include <hip/hip_runtime.h>
#include <hip/hip_bf16.h>

typedef __attribute__((ext_vector_type(8))) __bf16 bf16x8;
typedef __attribute__((ext_vector_type(2))) __bf16 bf16x2;
typedef __attribute__((ext_vector_type(4))) float floatx4;
typedef __attribute__((ext_vector_type(4))) unsigned short us4;
typedef __attribute__((ext_vector_type(8))) unsigned short us8;
typedef __attribute__((ext_vector_type(4))) short s16x4;
typedef __attribute__((ext_vector_type(2))) unsigned int uint2v;
typedef __attribute__((ext_vector_type(4))) unsigned int uint4v;

#define MFMA16(A, B, C) __builtin_amdgcn_mfma_f32_16x16x32_bf16((A), (B), (C), 0, 0, 0)
#define MFMA1K(A, B, C) __builtin_amdgcn_mfma_f32_16x16x16bf16_1k((A), (B), (C), 0, 0, 0)

#define LOG2E 1.44269504088896340736f

#if __has_builtin(__builtin_amdgcn_exp2f)
#define EXP2F(x) __builtin_amdgcn_exp2f(x)
#else
#define EXP2F(x) exp2f(x)
#endif

static __device__ __forceinline__ unsigned short f2bfbits(float f) {
    __hip_bfloat16 h = __float2bfloat16(f);
    union { __hip_bfloat16 h; unsigned short u; } cv;
    cv.h = h;
    return cv.u;
}
// fast bf16 RNE (finite moderate values only)
static __device__ __forceinline__ unsigned int rne32(float f) {
    unsigned int u = __builtin_bit_cast(unsigned int, f);
    return u + 0x7fffu + ((u >> 16) & 1u);
}
static __device__ __forceinline__ unsigned short rne16(float f) {
    return (unsigned short)(rne32(f) >> 16);
}

#if __has_builtin(__builtin_amdgcn_cvt_pk_bf16_f32)
static __device__ __forceinline__ s16x4 pack4(float e0, float e1, float e2, float e3) {
    bf16x2 lo = __builtin_amdgcn_cvt_pk_bf16_f32(e0, e1);
    bf16x2 hi = __builtin_amdgcn_cvt_pk_bf16_f32(e2, e3);
    uint2v u = {__builtin_bit_cast(unsigned int, lo), __builtin_bit_cast(unsigned int, hi)};
    return __builtin_bit_cast(s16x4, u);
}
static __device__ __forceinline__ bf16x8 cvt8(floatx4 a, floatx4 b) {
    bf16x2 p0 = __builtin_amdgcn_cvt_pk_bf16_f32(a[0], a[1]);
    bf16x2 p1 = __builtin_amdgcn_cvt_pk_bf16_f32(a[2], a[3]);
    bf16x2 p2 = __builtin_amdgcn_cvt_pk_bf16_f32(b[0], b[1]);
    bf16x2 p3 = __builtin_amdgcn_cvt_pk_bf16_f32(b[2], b[3]);
    uint4v u = {__builtin_bit_cast(unsigned int, p0), __builtin_bit_cast(unsigned int, p1),
                __builtin_bit_cast(unsigned int, p2), __builtin_bit_cast(unsigned int, p3)};
    return __builtin_bit_cast(bf16x8, u);
}
#else
static __device__ __forceinline__ s16x4 pack4(float e0, float e1, float e2, float e3) {
    unsigned int pa = __builtin_amdgcn_perm(rne32(e1), rne32(e0), 0x07060302u);
    unsigned int pb = __builtin_amdgcn_perm(rne32(e3), rne32(e2), 0x07060302u);
    uint2v u = {pa, pb};
    return __builtin_bit_cast(s16x4, u);
}
static __device__ __forceinline__ bf16x8 cvt8(floatx4 a, floatx4 b) {
    us8 u;
#pragma unroll
    for (int i = 0; i < 4; i++) { u[i] = rne16(a[i]); u[4 + i] = rne16(b[i]); }
    return __builtin_bit_cast(bf16x8, u);
}
#endif

static __device__ __forceinline__ bf16x8 load_bf8(const __hip_bfloat16* p) {
    return *reinterpret_cast<const bf16x8*>(p);
}
static __device__ __forceinline__ float bf2f(unsigned short u) {
    unsigned int w = ((unsigned int)u) << 16;
    return __builtin_bit_cast(float, w);
}

// Fragment layouts (16-row tile = 1024 bf16):
//   qf/kf[tile][h(2)][lane(64)][e(8)]: M[tile*16 + (lane&15)][h*32 + (lane>>4)*8 + e]
//   vf[tile][t(4)][lane(64)][e(4)]:  V[tile*16 + (lane>>4)*4 + e][t*16 + (lane&15)]
//   vfs[tile][lane(64)][t(4)][e(4)] (paired): one dwordx4 = two MFMA1K B-frags
// K is pre-scaled by log2(e) (weights+bias) so exp(s) == exp2(s').

// ---------------------------------------------------------------------------
// K1: QKV projection with fused weight prep. Block = one proj p x 4 tiles.
// Weight panel wT[p][d][c] = dw[c]*pw[c][d]*scale computed into LDS
// (XOR-swizzled by (row&7)<<3 elems to break the 512B-stride bank conflict).
// ---------------------------------------------------------------------------
__global__ __launch_bounds__(256) void proj_qkv(
    const float* __restrict__ x,
    const float* __restrict__ dwq, const float* __restrict__ pwq,
    const float* __restrict__ dwk, const float* __restrict__ pwk,
    const float* __restrict__ dwv, const float* __restrict__ pwv,
    const float* __restrict__ bqp, const float* __restrict__ bkp,
    const float* __restrict__ bvp,
    __hip_bfloat16* __restrict__ qf, __hip_bfloat16* __restrict__ kf,
    __hip_bfloat16* __restrict__ vf)
{
    __shared__ __hip_bfloat16 wle[16384];   // 32 KB panel [d=64][c=256]
    int b = blockIdx.x;          // 768 blocks
    int p = b >> 8;              // 0=q 1=k 2=v
    int tg = b & 255;
    int tid = threadIdx.x;

    const float* dw = (p == 0) ? dwq : ((p == 1) ? dwk : dwv);
    const float* pw = (p == 0) ? pwq : ((p == 1) ? pwk : pwv);
    float scale = (p == 1) ? LOG2E : 1.0f;

    {
        float dwc = dw[tid];     // c = tid for every fill iteration
#pragma unroll
        for (int k = 0; k < 64; k++) {
            int idx = (k * 256 + tid) ^ ((k & 7) << 3);
            wle[idx] = __float2bfloat16(dwc * pw[tid * 64 + k] * scale);
        }
    }
    __syncthreads();

    int wv = tid >> 6;
    int wid = tg * 4 + wv;       // tile 0..1023
    int lane = tid & 63;
    int l15 = lane & 15, quad = lane >> 4;

    floatx4 acc[4];
#pragma unroll
    for (int t = 0; t < 4; t++) acc[t] = (floatx4){0.f, 0.f, 0.f, 0.f};

    const float* xrow = x + (wid * 16 + l15) * 256 + quad * 8;
#pragma unroll
    for (int ks = 0; ks < 8; ks++) {
        floatx4 xa = *reinterpret_cast<const floatx4*>(xrow + ks * 32);
        floatx4 xb = *reinterpret_cast<const floatx4*>(xrow + ks * 32 + 4);
        bf16x8 a = cvt8(xa, xb);
#pragma unroll
        for (int t = 0; t < 4; t++) {
            int j0 = ((t * 16 + l15) * 256 + ks * 32 + quad * 8) ^ ((l15 & 7) << 3);
            bf16x8 bfr = *reinterpret_cast<const bf16x8*>(&wle[j0]);
            acc[t] = MFMA16(a, bfr, acc[t]);
        }
    }
    if (p < 2) {
        __hip_bfloat16* dst = (p == 0) ? qf : kf;
        const float* bias = (p == 0) ? bqp : bkp;
        float bscale = (p == 1) ? LOG2E : 1.0f;
#pragma unroll
        for (int t = 0; t < 4; t++) {
            float bsv = bias[t * 16 + l15] * bscale;
            int off0 = wid * 1024 + (t >> 1) * 512 +
                       (((((t & 1) << 1) | (l15 >> 3)) * 16 + quad * 4) * 8) + (l15 & 7);
#pragma unroll
            for (int r = 0; r < 4; r++)
                dst[off0 + r * 8] = __float2bfloat16(acc[t][r] + bsv);
        }
    } else {
#pragma unroll
        for (int t = 0; t < 4; t++) {
            float bsv = bvp[t * 16 + l15];
            us4 pk;
#pragma unroll
            for (int r = 0; r < 4; r++) pk[r] = f2bfbits(acc[t][r] + bsv);
            *reinterpret_cast<us4*>(vf + (wid * 4 + t) * 256 + lane * 4) = pk;
        }
    }
}

// ---------------------------------------------------------------------------
// K2: 512 blocks x 512 thr; block = 2 i-tiles (K-frag reuse), 8 waves split j.
// Depth-2 software pipeline on the Q-fragment loads (latency-bound loop:
// ~150 cyc compute/iter vs ~200-500 cyc L2 latency). Prefetch may read up to
// 2 tiles past this wave's j-range -> still inside workspace, values unused.
// ---------------------------------------------------------------------------
#define P1STEP(B0, B1, B2, B3) do {                                        \
    floatx4 z = (floatx4){0.f, 0.f, 0.f, 0.f};                             \
    floatx4 sA0 = MFMA16(a1, (B1), MFMA16(a0, (B0), z));                   \
    floatx4 sA1 = MFMA16(a1, (B3), MFMA16(a0, (B2), z));                   \
    floatx4 sB0 = MFMA16(a3, (B1), MFMA16(a2, (B0), z));                   \
    floatx4 sB1 = MFMA16(a3, (B3), MFMA16(a2, (B2), z));                   \
    _Pragma("unroll")                                                      \
    for (int r = 0; r < 4; r++) {                                          \
        lsA[r] += EXP2F(sA0[r]) + EXP2F(sA1[r]);                           \
        lsB[r] += EXP2F(sB0[r]) + EXP2F(sB1[r]);                           \
    }                                                                      \
} while (0)

__global__ __launch_bounds__(512) void pass1_rl(
    const __hip_bfloat16* __restrict__ qf, const __hip_bfloat16* __restrict__ kf,
    const __hip_bfloat16* __restrict__ vf, __hip_bfloat16* __restrict__ vfs)
{
    int itg0 = blockIdx.x * 2;            // i-tiles itg0, itg0+1 (same n)
    int n = itg0 >> 8;
    int jw = threadIdx.x >> 6;            // 0..7
    int lane = threadIdx.x & 63;
    int l15 = lane & 15, quad = lane >> 4;

    const __hip_bfloat16* kp = kf + itg0 * 1024 + lane * 8;
    bf16x8 a0 = load_bf8(kp);
    bf16x8 a1 = load_bf8(kp + 512);
    bf16x8 a2 = load_bf8(kp + 1024);
    bf16x8 a3 = load_bf8(kp + 1536);

    floatx4 lsA = (floatx4){0.f, 0.f, 0.f, 0.f};
    floatx4 lsB = (floatx4){0.f, 0.f, 0.f, 0.f};
    const __hip_bfloat16* qp0 = qf + (n * 256 + jw * 32) * 1024 + lane * 8;

    // stage 0 = iter it, stage 1 = iter it+1 (each iter covers 2 j-tiles)
    bf16x8 s0b0 = load_bf8(qp0);
    bf16x8 s0b1 = load_bf8(qp0 + 512);
    bf16x8 s0b2 = load_bf8(qp0 + 1024);
    bf16x8 s0b3 = load_bf8(qp0 + 1536);
    bf16x8 s1b0 = load_bf8(qp0 + 2048);
    bf16x8 s1b1 = load_bf8(qp0 + 2560);
    bf16x8 s1b2 = load_bf8(qp0 + 3072);
    bf16x8 s1b3 = load_bf8(qp0 + 3584);

    for (int it = 0; it < 16; it += 2) {
        bf16x8 n0 = load_bf8(qp0 + 4096);
        bf16x8 n1 = load_bf8(qp0 + 4608);
        bf16x8 n2 = load_bf8(qp0 + 5120);
        bf16x8 n3 = load_bf8(qp0 + 5632);
        P1STEP(s0b0, s0b1, s0b2, s0b3);
        s0b0 = n0; s0b1 = n1; s0b2 = n2; s0b3 = n3;
        bf16x8 m0 = load_bf8(qp0 + 6144);
        bf16x8 m1 = load_bf8(qp0 + 6656);
        bf16x8 m2 = load_bf8(qp0 + 7168);
        bf16x8 m3 = load_bf8(qp0 + 7680);
        P1STEP(s1b0, s1b1, s1b2, s1b3);
        s1b0 = m0; s1b1 = m1; s1b2 = m2; s1b3 = m3;
        qp0 += 4096;
    }
#pragma unroll
    for (int m = 1; m < 16; m <<= 1) {
#pragma unroll
        for (int r = 0; r < 4; r++) {
            lsA[r] += __shfl_xor(lsA[r], m, 64);
            lsB[r] += __shfl_xor(lsB[r], m, 64);
        }
    }
    __shared__ float red[8][32];
    __shared__ float rls[32];
    if (l15 == 0) {
#pragma unroll
        for (int r = 0; r < 4; r++) {
            red[jw][quad * 4 + r] = lsA[r];
            red[jw][16 + quad * 4 + r] = lsB[r];
        }
    }
    __syncthreads();
    if (threadIdx.x < 32) {
        float tot = 0.f;
#pragma unroll
        for (int w = 0; w < 8; w++) tot += red[w][threadIdx.x];
        rls[threadIdx.x] = 1.0f / tot;
    }
    __syncthreads();
    // vfs(paired) = vf * rl(row); input elem m (within tile): t=m>>8,
    // l=(m>>2)&63, e=m&3; row=(l>>4)*4+e; out idx = l*16 + t*4 + e.
    int m0 = threadIdx.x * 4;             // 0..2044, covers 2 tiles
    int toff = m0 >> 10;                  // 0/1
    int mm = m0 & 1023;
    int t = mm >> 8;
    int l = (mm >> 2) & 63;
    int rb = toff * 16 + (l >> 4) * 4;
    us4 vv = *reinterpret_cast<const us4*>(
        reinterpret_cast<const unsigned short*>(vf) + itg0 * 1024 + m0);
    us4 ov;
#pragma unroll
    for (int r = 0; r < 4; r++) ov[r] = rne16(bf2f(vv[r]) * rls[rb + r]);
    *reinterpret_cast<us4*>(
        reinterpret_cast<unsigned short*>(vfs) + (itg0 + toff) * 1024 + l * 16 + t * 4) = ov;
}

// ---------------------------------------------------------------------------
// K3: attT partials. 512 blocks x 256; wave = 4 j-tiles, 32 i-iters, NPART=8.
// MfmaUtil-calibrated floor ~10us; the rest was per-iter load latency ->
// depth-2 pipeline (2-step unrolled loop, named stage regs). Prefetch reads
// up to 2 tiles past the ih-range: workspace-valid, values unused.
// XCD-swizzle colocates the 16 jg-blocks sharing one (n,ih) K/V range.
// ---------------------------------------------------------------------------
#define P2STEP(KA, KB, VA, VB) do {                                            \
    floatx4 z = (floatx4){0.f, 0.f, 0.f, 0.f};                                 \
    floatx4 s0 = MFMA16((KB), bq0b, MFMA16((KA), bq0a, z));                    \
    floatx4 s1 = MFMA16((KB), bq1b, MFMA16((KA), bq1a, z));                    \
    floatx4 s2 = MFMA16((KB), bq2b, MFMA16((KA), bq2a, z));                    \
    floatx4 s3 = MFMA16((KB), bq3b, MFMA16((KA), bq3a, z));                    \
    s16x4 p0 = pack4(EXP2F(s0[0]), EXP2F(s0[1]), EXP2F(s0[2]), EXP2F(s0[3])); \
    s16x4 p1 = pack4(EXP2F(s1[0]), EXP2F(s1[1]), EXP2F(s1[2]), EXP2F(s1[3])); \
    s16x4 p2 = pack4(EXP2F(s2[0]), EXP2F(s2[1]), EXP2F(s2[2]), EXP2F(s2[3])); \
    s16x4 p3 = pack4(EXP2F(s3[0]), EXP2F(s3[1]), EXP2F(s3[2]), EXP2F(s3[3])); \
    s16x4 bv0 = __builtin_bit_cast(s16x4, __builtin_shufflevector((VA), (VA), 0, 1, 2, 3)); \
    s16x4 bv1 = __builtin_bit_cast(s16x4, __builtin_shufflevector((VA), (VA), 4, 5, 6, 7)); \
    s16x4 bv2 = __builtin_bit_cast(s16x4, __builtin_shufflevector((VB), (VB), 0, 1, 2, 3)); \
    s16x4 bv3 = __builtin_bit_cast(s16x4, __builtin_shufflevector((VB), (VB), 4, 5, 6, 7)); \
    acc0[0] = MFMA1K(p0, bv0, acc0[0]);                                        \
    acc1[0] = MFMA1K(p1, bv0, acc1[0]);                                        \
    acc2[0] = MFMA1K(p2, bv0, acc2[0]);                                        \
    acc3[0] = MFMA1K(p3, bv0, acc3[0]);                                        \
    acc0[1] = MFMA1K(p0, bv1, acc0[1]);                                        \
    acc1[1] = MFMA1K(p1, bv1, acc1[1]);                                        \
    acc2[1] = MFMA1K(p2, bv1, acc2[1]);                                        \
    acc3[1] = MFMA1K(p3, bv1, acc3[1]);                                        \
    acc0[2] = MFMA1K(p0, bv2, acc0[2]);                                        \
    acc1[2] = MFMA1K(p1, bv2, acc1[2]);                                        \
    acc2[2] = MFMA1K(p2, bv2, acc2[2]);                                        \
    acc3[2] = MFMA1K(p3, bv2, acc3[2]);                                        \
    acc0[3] = MFMA1K(p0, bv3, acc0[3]);                                        \
    acc1[3] = MFMA1K(p1, bv3, acc1[3]);                                        \
    acc2[3] = MFMA1K(p2, bv3, acc2[3]);                                        \
    acc3[3] = MFMA1K(p3, bv3, acc3[3]);                                        \
} while (0)

__global__ __launch_bounds__(256) void pass2_att(
    const __hip_bfloat16* __restrict__ qf, const __hip_bfloat16* __restrict__ kf,
    const __hip_bfloat16* __restrict__ vfs,
    unsigned short* __restrict__ attp)
{
    int b = blockIdx.x;          // 512
    // bijective XCD-aware decode: 16 jg-blocks of one (n,ih) on one XCD
    int xcd = b & 7, slot = b >> 3;
    int g = xcd + 8 * (slot >> 4);   // 0..31
    int jg = slot & 15;
    int n = g >> 3, ih = g & 7;
    int w = threadIdx.x >> 6;
    int jt0 = jg * 16 + w * 4;   // local j-tiles jt0..jt0+3
    int lane = threadIdx.x & 63;
    int l15 = lane & 15, quad = lane >> 4;

    const __hip_bfloat16* qp = qf + (n * 256 + jt0) * 1024 + lane * 8;
    bf16x8 bq0a = load_bf8(qp);
    bf16x8 bq0b = load_bf8(qp + 512);
    bf16x8 bq1a = load_bf8(qp + 1024);
    bf16x8 bq1b = load_bf8(qp + 1536);
    bf16x8 bq2a = load_bf8(qp + 2048);
    bf16x8 bq2b = load_bf8(qp + 2560);
    bf16x8 bq3a = load_bf8(qp + 3072);
    bf16x8 bq3b = load_bf8(qp + 3584);

    floatx4 acc0[4], acc1[4], acc2[4], acc3[4];
#pragma unroll
    for (int t = 0; t < 4; t++) {
        acc0[t] = (floatx4){0.f, 0.f, 0.f, 0.f};
        acc1[t] = (floatx4){0.f, 0.f, 0.f, 0.f};
        acc2[t] = (floatx4){0.f, 0.f, 0.f, 0.f};
        acc3[t] = (floatx4){0.f, 0.f, 0.f, 0.f};
    }

    int it0 = n * 256 + ih * 32;
    const __hip_bfloat16* kp = kf + it0 * 1024 + lane * 8;
    const __hip_bfloat16* vp = vfs + it0 * 1024 + lane * 16;

    // stage 0 = tile it, stage 1 = tile it+1
    bf16x8 kA0 = load_bf8(kp);
    bf16x8 kB0 = load_bf8(kp + 512);
    us8 vA0 = *reinterpret_cast<const us8*>(vp);
    us8 vB0 = *reinterpret_cast<const us8*>(vp + 8);
    bf16x8 kA1 = load_bf8(kp + 1024);
    bf16x8 kB1 = load_bf8(kp + 1536);
    us8 vA1 = *reinterpret_cast<const us8*>(vp + 1024);
    us8 vB1 = *reinterpret_cast<const us8*>(vp + 1024 + 8);

    for (int it = 0; it < 32; it += 2) {
        bf16x8 nkA = load_bf8(kp + 2048);
        bf16x8 nkB = load_bf8(kp + 2560);
        us8 nvA = *reinterpret_cast<const us8*>(vp + 2048);
        us8 nvB = *reinterpret_cast<const us8*>(vp + 2048 + 8);
        P2STEP(kA0, kB0, vA0, vB0);
        kA0 = nkA; kB0 = nkB; vA0 = nvA; vB0 = nvB;
        bf16x8 mkA = load_bf8(kp + 3072);
        bf16x8 mkB = load_bf8(kp + 3584);
        us8 mvA = *reinterpret_cast<const us8*>(vp + 3072);
        us8 mvB = *reinterpret_cast<const us8*>(vp + 3072 + 8);
        P2STEP(kA1, kB1, vA1, vB1);
        kA1 = mkA; kB1 = mkB; vA1 = mvA; vB1 = mvB;
        kp += 2048; vp += 2048;
    }
    unsigned short* op0 = attp + ih * 1048576;
#pragma unroll
    for (int t = 0; t < 4; t++) {
        s16x4 k0 = pack4(acc0[t][0], acc0[t][1], acc0[t][2], acc0[t][3]);
        s16x4 k1 = pack4(acc1[t][0], acc1[t][1], acc1[t][2], acc1[t][3]);
        s16x4 k2 = pack4(acc2[t][0], acc2[t][1], acc2[t][2], acc2[t][3]);
        s16x4 k3 = pack4(acc3[t][0], acc3[t][1], acc3[t][2], acc3[t][3]);
        unsigned short* op = op0 + (n * 64 + t * 16 + l15) * 4096 + jt0 * 16 + quad * 4;
        *reinterpret_cast<s16x4*>(op) = k0;
        *reinterpret_cast<s16x4*>(op + 16) = k1;
        *reinterpret_cast<s16x4*>(op + 32) = k2;
        *reinterpret_cast<s16x4*>(op + 48) = k3;
    }
}

// ---------------------------------------------------------------------------
// K4: final sepconv + residual, summing NPART bf16 i-partials.
// Partial reduction uses paired dword loads (2 jj per thread).
// ---------------------------------------------------------------------------
template<int NPART>
__global__ __launch_bounds__(256) void final_out(
    const unsigned short* __restrict__ attp, const float* __restrict__ gco,
    const float* __restrict__ dwa, const float* __restrict__ pwa,
    const float* __restrict__ ba, float* __restrict__ out)
{
    int b = blockIdx.x;       // 2048 blocks
    int n = b >> 9;
    int hh = (b >> 3) & 63;
    int w0 = (b & 7) << 3;
    __shared__ float g[512];
    int tid = threadIdx.x;
    const unsigned short* ap = attp + (n * 64 + hh) * 4096 + w0 * 64;
    {
        int jj0 = tid * 2;    // 256 threads x 2 = 512
        float v0 = 0.f, v1 = 0.f;
#pragma unroll
        for (int ph = 0; ph < NPART; ph++) {
            unsigned int u = *reinterpret_cast<const unsigned int*>(ap + ph * 1048576 + jj0);
            v0 += bf2f((unsigned short)(u & 0xffffu));
            v1 += bf2f((unsigned short)(u >> 16));
        }
        g[jj0] = v0 * dwa[jj0 & 63];
        g[jj0 + 1] = v1 * dwa[(jj0 + 1) & 63];
    }
    __syncthreads();
    float acc[8];
#pragma unroll
    for (int w = 0; w < 8; w++) acc[w] = 0.f;
    for (int cc = 0; cc < 64; cc++) {
        float p = pwa[cc * 256 + tid];
#pragma unroll
        for (int w = 0; w < 8; w++) acc[w] += g[w * 64 + cc] * p;
    }
    float bb = ba[tid];
#pragma unroll
    for (int w = 0; w < 8; w++) {
        int pos = (n * 64 + hh) * 64 + w0 + w;
        float gv = gco[pos * 256 + tid];
        out[pos * 256 + tid] = gv * (acc[w] + bb) + gv;
    }
}

// ---------------------------------------------------------------------------
extern "C" void kernel_launch(void* const* d_in, const int* in_sizes, int n_in,
                              void* d_out, int out_size, void* d_ws, size_t ws_size,
                              hipStream_t stream) {
    const float* x   = (const float*)d_in[0];
    const float* gco = (const float*)d_in[1];
    const float* dwq = (const float*)d_in[2];
    const float* pwq = (const float*)d_in[3];
    const float* bq  = (const float*)d_in[4];
    const float* dwk = (const float*)d_in[5];
    const float* pwk = (const float*)d_in[6];
    const float* bk  = (const float*)d_in[7];
    const float* dwv = (const float*)d_in[8];
    const float* pwv = (const float*)d_in[9];
    const float* bv  = (const float*)d_in[10];
    const float* dwa = (const float*)d_in[11];
    const float* pwa = (const float*)d_in[12];
    const float* ba  = (const float*)d_in[13];
    float* out = (float*)d_out;

    char* ws = (char*)d_ws;
    __hip_bfloat16* qf  = (__hip_bfloat16*)(ws + 98304);          // 2 MB
    __hip_bfloat16* kf  = (__hip_bfloat16*)(ws + 2195456);        // 2 MB
    __hip_bfloat16* vf  = (__hip_bfloat16*)(ws + 4292608);        // 2 MB
    __hip_bfloat16* vfs = (__hip_bfloat16*)(ws + 6389760);        // 2 MB
    unsigned short* attp = (unsigned short*)(ws + 8486912);       // 8 x 2 MB bf16

    proj_qkv<<<768, 256, 0, stream>>>(x, dwq, pwq, dwk, pwk, dwv, pwv,
                                      bq, bk, bv, qf, kf, vf);
    pass1_rl<<<512, 512, 0, stream>>>(qf, kf, vf, vfs);
    pass2_att<<<512, 256, 0, stream>>>(qf, kf, vfs, attp);
    final_out<8><<<2048, 256, 0, stream>>>(attp, gco, dwa, pwa, ba, out);
}

// Round 6
// 165.668 us; speedup vs baseline: 1.8024x; 1.0243x over previous
//
#include <hip/hip_runtime.h>
#include <hip/hip_bf16.h>

typedef __attribute__((ext_vector_type(8))) __bf16 bf16x8;
typedef __attribute__((ext_vector_type(2))) __bf16 bf16x2;
typedef __attribute__((ext_vector_type(4))) float floatx4;
typedef __attribute__((ext_vector_type(4))) unsigned short us4;
typedef __attribute__((ext_vector_type(8))) unsigned short us8;
typedef __attribute__((ext_vector_type(4))) short s16x4;
typedef __attribute__((ext_vector_type(2))) unsigned int uint2v;
typedef __attribute__((ext_vector_type(4))) unsigned int uint4v;

#define MFMA16(A, B, C) __builtin_amdgcn_mfma_f32_16x16x32_bf16((A), (B), (C), 0, 0, 0)
#define MFMA1K(A, B, C) __builtin_amdgcn_mfma_f32_16x16x16bf16_1k((A), (B), (C), 0, 0, 0)

#define LOG2E 1.44269504088896340736f

#if __has_builtin(__builtin_amdgcn_exp2f)
#define EXP2F(x) __builtin_amdgcn_exp2f(x)
#else
#define EXP2F(x) exp2f(x)
#endif

static __device__ __forceinline__ unsigned short f2bfbits(float f) {
    __hip_bfloat16 h = __float2bfloat16(f);
    union { __hip_bfloat16 h; unsigned short u; } cv;
    cv.h = h;
    return cv.u;
}
// fast bf16 RNE (finite moderate values only)
static __device__ __forceinline__ unsigned int rne32(float f) {
    unsigned int u = __builtin_bit_cast(unsigned int, f);
    return u + 0x7fffu + ((u >> 16) & 1u);
}
static __device__ __forceinline__ unsigned short rne16(float f) {
    return (unsigned short)(rne32(f) >> 16);
}

#if __has_builtin(__builtin_amdgcn_cvt_pk_bf16_f32)
static __device__ __forceinline__ s16x4 pack4(float e0, float e1, float e2, float e3) {
    bf16x2 lo = __builtin_amdgcn_cvt_pk_bf16_f32(e0, e1);
    bf16x2 hi = __builtin_amdgcn_cvt_pk_bf16_f32(e2, e3);
    uint2v u = {__builtin_bit_cast(unsigned int, lo), __builtin_bit_cast(unsigned int, hi)};
    return __builtin_bit_cast(s16x4, u);
}
static __device__ __forceinline__ bf16x8 cvt8(floatx4 a, floatx4 b) {
    bf16x2 p0 = __builtin_amdgcn_cvt_pk_bf16_f32(a[0], a[1]);
    bf16x2 p1 = __builtin_amdgcn_cvt_pk_bf16_f32(a[2], a[3]);
    bf16x2 p2 = __builtin_amdgcn_cvt_pk_bf16_f32(b[0], b[1]);
    bf16x2 p3 = __builtin_amdgcn_cvt_pk_bf16_f32(b[2], b[3]);
    uint4v u = {__builtin_bit_cast(unsigned int, p0), __builtin_bit_cast(unsigned int, p1),
                __builtin_bit_cast(unsigned int, p2), __builtin_bit_cast(unsigned int, p3)};
    return __builtin_bit_cast(bf16x8, u);
}
#else
static __device__ __forceinline__ s16x4 pack4(float e0, float e1, float e2, float e3) {
    unsigned int pa = __builtin_amdgcn_perm(rne32(e1), rne32(e0), 0x07060302u);
    unsigned int pb = __builtin_amdgcn_perm(rne32(e3), rne32(e2), 0x07060302u);
    uint2v u = {pa, pb};
    return __builtin_bit_cast(s16x4, u);
}
static __device__ __forceinline__ bf16x8 cvt8(floatx4 a, floatx4 b) {
    us8 u;
#pragma unroll
    for (int i = 0; i < 4; i++) { u[i] = rne16(a[i]); u[4 + i] = rne16(b[i]); }
    return __builtin_bit_cast(bf16x8, u);
}
#endif

static __device__ __forceinline__ bf16x8 load_bf8(const __hip_bfloat16* p) {
    return *reinterpret_cast<const bf16x8*>(p);
}
static __device__ __forceinline__ float bf2f(unsigned short u) {
    unsigned int w = ((unsigned int)u) << 16;
    return __builtin_bit_cast(float, w);
}

// async global->LDS, 16B per lane; lds dest must be wave-uniform base.
static __device__ __forceinline__ void gld16(const void* g, void* l) {
    __builtin_amdgcn_global_load_lds(
        (const __attribute__((address_space(1))) unsigned int*)g,
        (__attribute__((address_space(3))) unsigned int*)l, 16, 0, 0);
}

// Fragment layouts (16-row tile = 1024 bf16):
//   qf/kf[tile][h(2)][lane(64)][e(8)]: M[tile*16 + (lane&15)][h*32 + (lane>>4)*8 + e]
//   vf[tile][t(4)][lane(64)][e(4)]:  V[tile*16 + (lane>>4)*4 + e][t*16 + (lane&15)]
//   vfs[tile] NEW pairing for stride-16 LDS reads:
//     shorts idx = (t>>1)*512 + lane*8 + (t&1)*4 + e
//     -> first 1KB = {t0,t1} per lane (v01), second 1KB = {t2,t3} (v23)
// K is pre-scaled by log2(e) (weights+bias) so exp(s) == exp2(s').

// ---------------------------------------------------------------------------
// K1: QKV projection with fused weight prep (unchanged from R5).
// ---------------------------------------------------------------------------
__global__ __launch_bounds__(256) void proj_qkv(
    const float* __restrict__ x,
    const float* __restrict__ dwq, const float* __restrict__ pwq,
    const float* __restrict__ dwk, const float* __restrict__ pwk,
    const float* __restrict__ dwv, const float* __restrict__ pwv,
    const float* __restrict__ bqp, const float* __restrict__ bkp,
    const float* __restrict__ bvp,
    __hip_bfloat16* __restrict__ qf, __hip_bfloat16* __restrict__ kf,
    __hip_bfloat16* __restrict__ vf)
{
    __shared__ __hip_bfloat16 wle[16384];   // 32 KB panel [d=64][c=256]
    int b = blockIdx.x;          // 768 blocks
    int p = b >> 8;              // 0=q 1=k 2=v
    int tg = b & 255;
    int tid = threadIdx.x;

    const float* dw = (p == 0) ? dwq : ((p == 1) ? dwk : dwv);
    const float* pw = (p == 0) ? pwq : ((p == 1) ? pwk : pwv);
    float scale = (p == 1) ? LOG2E : 1.0f;

    {
        float dwc = dw[tid];     // c = tid for every fill iteration
#pragma unroll
        for (int k = 0; k < 64; k++) {
            int idx = (k * 256 + tid) ^ ((k & 7) << 3);
            wle[idx] = __float2bfloat16(dwc * pw[tid * 64 + k] * scale);
        }
    }
    __syncthreads();

    int wv = tid >> 6;
    int wid = tg * 4 + wv;       // tile 0..1023
    int lane = tid & 63;
    int l15 = lane & 15, quad = lane >> 4;

    floatx4 acc[4];
#pragma unroll
    for (int t = 0; t < 4; t++) acc[t] = (floatx4){0.f, 0.f, 0.f, 0.f};

    const float* xrow = x + (wid * 16 + l15) * 256 + quad * 8;
#pragma unroll
    for (int ks = 0; ks < 8; ks++) {
        floatx4 xa = *reinterpret_cast<const floatx4*>(xrow + ks * 32);
        floatx4 xb = *reinterpret_cast<const floatx4*>(xrow + ks * 32 + 4);
        bf16x8 a = cvt8(xa, xb);
#pragma unroll
        for (int t = 0; t < 4; t++) {
            int j0 = ((t * 16 + l15) * 256 + ks * 32 + quad * 8) ^ ((l15 & 7) << 3);
            bf16x8 bfr = *reinterpret_cast<const bf16x8*>(&wle[j0]);
            acc[t] = MFMA16(a, bfr, acc[t]);
        }
    }
    if (p < 2) {
        __hip_bfloat16* dst = (p == 0) ? qf : kf;
        const float* bias = (p == 0) ? bqp : bkp;
        float bscale = (p == 1) ? LOG2E : 1.0f;
#pragma unroll
        for (int t = 0; t < 4; t++) {
            float bsv = bias[t * 16 + l15] * bscale;
            int off0 = wid * 1024 + (t >> 1) * 512 +
                       (((((t & 1) << 1) | (l15 >> 3)) * 16 + quad * 4) * 8) + (l15 & 7);
#pragma unroll
            for (int r = 0; r < 4; r++)
                dst[off0 + r * 8] = __float2bfloat16(acc[t][r] + bsv);
        }
    } else {
#pragma unroll
        for (int t = 0; t < 4; t++) {
            float bsv = bvp[t * 16 + l15];
            us4 pk;
#pragma unroll
            for (int r = 0; r < 4; r++) pk[r] = f2bfbits(acc[t][r] + bsv);
            *reinterpret_cast<us4*>(vf + (wid * 4 + t) * 256 + lane * 4) = pk;
        }
    }
}

// ---------------------------------------------------------------------------
// K2: 512 blocks x 512 thr; block = 2 i-tiles (K-frag reuse), 8 waves split j.
// Depth-2 pipeline on Q loads (R5). Tail writes vfs in the NEW paired layout
// (stride-16 for pass2's LDS staging).
// ---------------------------------------------------------------------------
#define P1STEP(B0, B1, B2, B3) do {                                        \
    floatx4 z = (floatx4){0.f, 0.f, 0.f, 0.f};                             \
    floatx4 sA0 = MFMA16(a1, (B1), MFMA16(a0, (B0), z));                   \
    floatx4 sA1 = MFMA16(a1, (B3), MFMA16(a0, (B2), z));                   \
    floatx4 sB0 = MFMA16(a3, (B1), MFMA16(a2, (B0), z));                   \
    floatx4 sB1 = MFMA16(a3, (B3), MFMA16(a2, (B2), z));                   \
    _Pragma("unroll")                                                      \
    for (int r = 0; r < 4; r++) {                                          \
        lsA[r] += EXP2F(sA0[r]) + EXP2F(sA1[r]);                           \
        lsB[r] += EXP2F(sB0[r]) + EXP2F(sB1[r]);                           \
    }                                                                      \
} while (0)

__global__ __launch_bounds__(512) void pass1_rl(
    const __hip_bfloat16* __restrict__ qf, const __hip_bfloat16* __restrict__ kf,
    const __hip_bfloat16* __restrict__ vf, __hip_bfloat16* __restrict__ vfs)
{
    int itg0 = blockIdx.x * 2;            // i-tiles itg0, itg0+1 (same n)
    int n = itg0 >> 8;
    int jw = threadIdx.x >> 6;            // 0..7
    int lane = threadIdx.x & 63;
    int l15 = lane & 15, quad = lane >> 4;

    const __hip_bfloat16* kp = kf + itg0 * 1024 + lane * 8;
    bf16x8 a0 = load_bf8(kp);
    bf16x8 a1 = load_bf8(kp + 512);
    bf16x8 a2 = load_bf8(kp + 1024);
    bf16x8 a3 = load_bf8(kp + 1536);

    floatx4 lsA = (floatx4){0.f, 0.f, 0.f, 0.f};
    floatx4 lsB = (floatx4){0.f, 0.f, 0.f, 0.f};
    const __hip_bfloat16* qp0 = qf + (n * 256 + jw * 32) * 1024 + lane * 8;

    // stage 0 = iter it, stage 1 = iter it+1 (each iter covers 2 j-tiles)
    bf16x8 s0b0 = load_bf8(qp0);
    bf16x8 s0b1 = load_bf8(qp0 + 512);
    bf16x8 s0b2 = load_bf8(qp0 + 1024);
    bf16x8 s0b3 = load_bf8(qp0 + 1536);
    bf16x8 s1b0 = load_bf8(qp0 + 2048);
    bf16x8 s1b1 = load_bf8(qp0 + 2560);
    bf16x8 s1b2 = load_bf8(qp0 + 3072);
    bf16x8 s1b3 = load_bf8(qp0 + 3584);

    for (int it = 0; it < 16; it += 2) {
        bf16x8 n0 = load_bf8(qp0 + 4096);
        bf16x8 n1 = load_bf8(qp0 + 4608);
        bf16x8 n2 = load_bf8(qp0 + 5120);
        bf16x8 n3 = load_bf8(qp0 + 5632);
        P1STEP(s0b0, s0b1, s0b2, s0b3);
        s0b0 = n0; s0b1 = n1; s0b2 = n2; s0b3 = n3;
        bf16x8 m0 = load_bf8(qp0 + 6144);
        bf16x8 m1 = load_bf8(qp0 + 6656);
        bf16x8 m2 = load_bf8(qp0 + 7168);
        bf16x8 m3 = load_bf8(qp0 + 7680);
        P1STEP(s1b0, s1b1, s1b2, s1b3);
        s1b0 = m0; s1b1 = m1; s1b2 = m2; s1b3 = m3;
        qp0 += 4096;
    }
#pragma unroll
    for (int m = 1; m < 16; m <<= 1) {
#pragma unroll
        for (int r = 0; r < 4; r++) {
            lsA[r] += __shfl_xor(lsA[r], m, 64);
            lsB[r] += __shfl_xor(lsB[r], m, 64);
        }
    }
    __shared__ float red[8][32];
    __shared__ float rls[32];
    if (l15 == 0) {
#pragma unroll
        for (int r = 0; r < 4; r++) {
            red[jw][quad * 4 + r] = lsA[r];
            red[jw][16 + quad * 4 + r] = lsB[r];
        }
    }
    __syncthreads();
    if (threadIdx.x < 32) {
        float tot = 0.f;
#pragma unroll
        for (int w = 0; w < 8; w++) tot += red[w][threadIdx.x];
        rls[threadIdx.x] = 1.0f / tot;
    }
    __syncthreads();
    // vfs(NEW pairing) = vf * rl(row); input elem m (within tile): t=m>>8,
    // l=(m>>2)&63, e=m&3; row=(l>>4)*4+e;
    // out idx = (t>>1)*512 + l*8 + (t&1)*4 + e.
    int m0 = threadIdx.x * 4;             // 0..2044, covers 2 tiles
    int toff = m0 >> 10;                  // 0/1
    int mm = m0 & 1023;
    int t = mm >> 8;
    int l = (mm >> 2) & 63;
    int rb = toff * 16 + (l >> 4) * 4;
    us4 vv = *reinterpret_cast<const us4*>(
        reinterpret_cast<const unsigned short*>(vf) + itg0 * 1024 + m0);
    us4 ov;
#pragma unroll
    for (int r = 0; r < 4; r++) ov[r] = rne16(bf2f(vv[r]) * rls[rb + r]);
    int oidx = (t >> 1) * 512 + l * 8 + (t & 1) * 4;
    *reinterpret_cast<us4*>(
        reinterpret_cast<unsigned short*>(vfs) + (itg0 + toff) * 1024 + oidx) = ov;
}

// ---------------------------------------------------------------------------
// K3: attT partials. R0-R5 showed occupancy/ILP/prefetch barely move pass2;
// the remaining tax is REDUNDANT VMEM ISSUE: every wave loaded the same K/V
// (268 MB total, ~170 B/cyc through a ~128 B/cyc L1 port). Fix: LDS-stage
// K/V once per block (global_load_lds, double-buffered, 2 tiles/phase),
// 8 waves share. Grid = n(4) x jgrp(8) x ih(8) = 256 blocks x 512 thr,
// wave = 4 j-tiles, NPART=8 (ITERS=32).
// ---------------------------------------------------------------------------
#define P2STEP(KA, KB, VA, VB) do {                                            \
    floatx4 z = (floatx4){0.f, 0.f, 0.f, 0.f};                                 \
    floatx4 s0 = MFMA16((KB), bq0b, MFMA16((KA), bq0a, z));                    \
    floatx4 s1 = MFMA16((KB), bq1b, MFMA16((KA), bq1a, z));                    \
    floatx4 s2 = MFMA16((KB), bq2b, MFMA16((KA), bq2a, z));                    \
    floatx4 s3 = MFMA16((KB), bq3b, MFMA16((KA), bq3a, z));                    \
    s16x4 p0 = pack4(EXP2F(s0[0]), EXP2F(s0[1]), EXP2F(s0[2]), EXP2F(s0[3])); \
    s16x4 p1 = pack4(EXP2F(s1[0]), EXP2F(s1[1]), EXP2F(s1[2]), EXP2F(s1[3])); \
    s16x4 p2 = pack4(EXP2F(s2[0]), EXP2F(s2[1]), EXP2F(s2[2]), EXP2F(s2[3])); \
    s16x4 p3 = pack4(EXP2F(s3[0]), EXP2F(s3[1]), EXP2F(s3[2]), EXP2F(s3[3])); \
    s16x4 bv0 = __builtin_bit_cast(s16x4, __builtin_shufflevector((VA), (VA), 0, 1, 2, 3)); \
    s16x4 bv1 = __builtin_bit_cast(s16x4, __builtin_shufflevector((VA), (VA), 4, 5, 6, 7)); \
    s16x4 bv2 = __builtin_bit_cast(s16x4, __builtin_shufflevector((VB), (VB), 0, 1, 2, 3)); \
    s16x4 bv3 = __builtin_bit_cast(s16x4, __builtin_shufflevector((VB), (VB), 4, 5, 6, 7)); \
    acc0[0] = MFMA1K(p0, bv0, acc0[0]);                                        \
    acc1[0] = MFMA1K(p1, bv0, acc1[0]);                                        \
    acc2[0] = MFMA1K(p2, bv0, acc2[0]);                                        \
    acc3[0] = MFMA1K(p3, bv0, acc3[0]);                                        \
    acc0[1] = MFMA1K(p0, bv1, acc0[1]);                                        \
    acc1[1] = MFMA1K(p1, bv1, acc1[1]);                                        \
    acc2[1] = MFMA1K(p2, bv1, acc2[1]);                                        \
    acc3[1] = MFMA1K(p3, bv1, acc3[1]);                                        \
    acc0[2] = MFMA1K(p0, bv2, acc0[2]);                                        \
    acc1[2] = MFMA1K(p1, bv2, acc1[2]);                                        \
    acc2[2] = MFMA1K(p2, bv2, acc2[2]);                                        \
    acc3[2] = MFMA1K(p3, bv2, acc3[2]);                                        \
    acc0[3] = MFMA1K(p0, bv3, acc0[3]);                                        \
    acc1[3] = MFMA1K(p1, bv3, acc1[3]);                                        \
    acc2[3] = MFMA1K(p2, bv3, acc2[3]);                                        \
    acc3[3] = MFMA1K(p3, bv3, acc3[3]);                                        \
} while (0)

__global__ __launch_bounds__(512) void pass2_att(
    const __hip_bfloat16* __restrict__ qf, const __hip_bfloat16* __restrict__ kf,
    const __hip_bfloat16* __restrict__ vfs,
    unsigned short* __restrict__ attp)
{
    // double-buffered K/V: per buffer [K(a) 2KB | K(b) 2KB | V(a) 2KB | V(b) 2KB]
    __shared__ char ldsbuf[2][8192];
    int b = blockIdx.x;          // 256
    int ih = b & 7;
    int jgrp = (b >> 3) & 7;
    int n = b >> 6;
    int tid = threadIdx.x;
    int w = tid >> 6;            // 0..7
    int lane = tid & 63;
    int l15 = lane & 15, quad = lane >> 4;
    int jt0 = jgrp * 32 + w * 4; // local j-tiles jt0..jt0+3

    const __hip_bfloat16* qp = qf + (n * 256 + jt0) * 1024 + lane * 8;
    bf16x8 bq0a = load_bf8(qp);
    bf16x8 bq0b = load_bf8(qp + 512);
    bf16x8 bq1a = load_bf8(qp + 1024);
    bf16x8 bq1b = load_bf8(qp + 1536);
    bf16x8 bq2a = load_bf8(qp + 2048);
    bf16x8 bq2b = load_bf8(qp + 2560);
    bf16x8 bq3a = load_bf8(qp + 3072);
    bf16x8 bq3b = load_bf8(qp + 3584);

    floatx4 acc0[4], acc1[4], acc2[4], acc3[4];
#pragma unroll
    for (int t = 0; t < 4; t++) {
        acc0[t] = (floatx4){0.f, 0.f, 0.f, 0.f};
        acc1[t] = (floatx4){0.f, 0.f, 0.f, 0.f};
        acc2[t] = (floatx4){0.f, 0.f, 0.f, 0.f};
        acc3[t] = (floatx4){0.f, 0.f, 0.f, 0.f};
    }

    int it0 = n * 256 + ih * 32;
    // staging role of this wave: w<4 -> K halves, w>=4 -> V halves
    const char* gbase = (w < 4) ? (const char*)(kf + it0 * 1024)
                                : (const char*)(vfs + it0 * 1024);
    const char* gw = gbase + ((w >> 1) & 1) * 2048 + (w & 1) * 1024 + lane * 16;
    char* lw0 = &ldsbuf[0][w * 1024];
    char* lw1 = &ldsbuf[1][w * 1024];

    // prologue: stage phase 0 (tiles 0,1) into buf 0
    gld16(gw, lw0);
    __syncthreads();

    int cur = 0;
    for (int ph = 0; ph < 16; ph++) {
        if (ph < 15)
            gld16(gw + (ph + 1) * 4096, cur ? lw0 : lw1);
        const char* base = ldsbuf[cur];
#pragma unroll
        for (int t = 0; t < 2; t++) {
            bf16x8 a0 = *reinterpret_cast<const bf16x8*>(base + t * 2048 + lane * 16);
            bf16x8 a1 = *reinterpret_cast<const bf16x8*>(base + t * 2048 + 1024 + lane * 16);
            us8 v01 = *reinterpret_cast<const us8*>(base + 4096 + t * 2048 + lane * 16);
            us8 v23 = *reinterpret_cast<const us8*>(base + 4096 + t * 2048 + 1024 + lane * 16);
            P2STEP(a0, a1, v01, v23);
        }
        __syncthreads();   // drains staging vmcnt + all reads of buf done
        cur ^= 1;
    }
    unsigned short* op0 = attp + ih * 1048576;
#pragma unroll
    for (int t = 0; t < 4; t++) {
        s16x4 k0 = pack4(acc0[t][0], acc0[t][1], acc0[t][2], acc0[t][3]);
        s16x4 k1 = pack4(acc1[t][0], acc1[t][1], acc1[t][2], acc1[t][3]);
        s16x4 k2 = pack4(acc2[t][0], acc2[t][1], acc2[t][2], acc2[t][3]);
        s16x4 k3 = pack4(acc3[t][0], acc3[t][1], acc3[t][2], acc3[t][3]);
        unsigned short* op = op0 + (n * 64 + t * 16 + l15) * 4096 + jt0 * 16 + quad * 4;
        *reinterpret_cast<s16x4*>(op) = k0;
        *reinterpret_cast<s16x4*>(op + 16) = k1;
        *reinterpret_cast<s16x4*>(op + 32) = k2;
        *reinterpret_cast<s16x4*>(op + 48) = k3;
    }
}

// ---------------------------------------------------------------------------
// K4: final sepconv + residual, summing NPART bf16 i-partials.
// Partial reduction uses paired dword loads (2 jj per thread).
// ---------------------------------------------------------------------------
template<int NPART>
__global__ __launch_bounds__(256) void final_out(
    const unsigned short* __restrict__ attp, const float* __restrict__ gco,
    const float* __restrict__ dwa, const float* __restrict__ pwa,
    const float* __restrict__ ba, float* __restrict__ out)
{
    int b = blockIdx.x;       // 2048 blocks
    int n = b >> 9;
    int hh = (b >> 3) & 63;
    int w0 = (b & 7) << 3;
    __shared__ float g[512];
    int tid = threadIdx.x;
    const unsigned short* ap = attp + (n * 64 + hh) * 4096 + w0 * 64;
    {
        int jj0 = tid * 2;    // 256 threads x 2 = 512
        float v0 = 0.f, v1 = 0.f;
#pragma unroll
        for (int ph = 0; ph < NPART; ph++) {
            unsigned int u = *reinterpret_cast<const unsigned int*>(ap + ph * 1048576 + jj0);
            v0 += bf2f((unsigned short)(u & 0xffffu));
            v1 += bf2f((unsigned short)(u >> 16));
        }
        g[jj0] = v0 * dwa[jj0 & 63];
        g[jj0 + 1] = v1 * dwa[(jj0 + 1) & 63];
    }
    __syncthreads();
    float acc[8];
#pragma unroll
    for (int w = 0; w < 8; w++) acc[w] = 0.f;
    for (int cc = 0; cc < 64; cc++) {
        float p = pwa[cc * 256 + tid];
#pragma unroll
        for (int w = 0; w < 8; w++) acc[w] += g[w * 64 + cc] * p;
    }
    float bb = ba[tid];
#pragma unroll
    for (int w = 0; w < 8; w++) {
        int pos = (n * 64 + hh) * 64 + w0 + w;
        float gv = gco[pos * 256 + tid];
        out[pos * 256 + tid] = gv * (acc[w] + bb) + gv;
    }
}

// ---------------------------------------------------------------------------
extern "C" void kernel_launch(void* const* d_in, const int* in_sizes, int n_in,
                              void* d_out, int out_size, void* d_ws, size_t ws_size,
                              hipStream_t stream) {
    const float* x   = (const float*)d_in[0];
    const float* gco = (const float*)d_in[1];
    const float* dwq = (const float*)d_in[2];
    const float* pwq = (const float*)d_in[3];
    const float* bq  = (const float*)d_in[4];
    const float* dwk = (const float*)d_in[5];
    const float* pwk = (const float*)d_in[6];
    const float* bk  = (const float*)d_in[7];
    const float* dwv = (const float*)d_in[8];
    const float* pwv = (const float*)d_in[9];
    const float* bv  = (const float*)d_in[10];
    const float* dwa = (const float*)d_in[11];
    const float* pwa = (const float*)d_in[12];
    const float* ba  = (const float*)d_in[13];
    float* out = (float*)d_out;

    char* ws = (char*)d_ws;
    __hip_bfloat16* qf  = (__hip_bfloat16*)(ws + 98304);          // 2 MB
    __hip_bfloat16* kf  = (__hip_bfloat16*)(ws + 2195456);        // 2 MB
    __hip_bfloat16* vf  = (__hip_bfloat16*)(ws + 4292608);        // 2 MB
    __hip_bfloat16* vfs = (__hip_bfloat16*)(ws + 6389760);        // 2 MB
    unsigned short* attp = (unsigned short*)(ws + 8486912);       // 8 x 2 MB bf16

    proj_qkv<<<768, 256, 0, stream>>>(x, dwq, pwq, dwk, pwk, dwv, pwv,
                                      bq, bk, bv, qf, kf, vf);
    pass1_rl<<<512, 512, 0, stream>>>(qf, kf, vf, vfs);
    pass2_att<<<256, 512, 0, stream>>>(qf, kf, vfs, attp);
    final_out<8><<<2048, 256, 0, stream>>>(attp, gco, dwa, pwa, ba, out);
}